// Round 3
// baseline (38327.026 us; speedup 1.0000x reference)
//
#include <hip/hip_runtime.h>

// MultiScaleGRU: T=8192, NINP=128, NSTATE=1024, NCH=4, GH=256, NLAYER=3, NCLASS=10
#define T_SEQ 8192
#define NST   1024
#define GHH   256
#define LD_IG 3072   // 4 channels * 768 ig columns

typedef _Float16 f16x2 __attribute__((ext_vector_type(2)));

#if defined(__has_builtin)
#if __has_builtin(__builtin_amdgcn_fdot2)
#define HAVE_FDOT2 1
#endif
#endif

__device__ __forceinline__ float fdot2f(f16x2 a, f16x2 b, float c) {
#ifdef HAVE_FDOT2
  return __builtin_amdgcn_fdot2(a, b, c, false);
#else
  float d;
  asm("v_dot2_f32_f16 %0, %1, %2, %3" : "=v"(d) : "v"(a), "v"(b), "v"(c));
  return d;
#endif
}

// quad-lane XOR butterfly add via DPP (VALU pipe — keeps reduce off the LDS pipe)
template<int CTRL>
__device__ __forceinline__ float dpp_xor_add(float x) {
#if defined(__has_builtin) && __has_builtin(__builtin_amdgcn_update_dpp)
  int s = __builtin_amdgcn_update_dpp(0, __builtin_bit_cast(int, x), CTRL, 0xF, 0xF, true);
  return x + __builtin_bit_cast(float, s);
#else
  return x + __shfl_xor(x, (CTRL == 0xB1) ? 1 : 2, 64);
#endif
}

__device__ __forceinline__ float sigmoid_f(float x) {
  return 1.0f / (1.0f + __expf(-x));
}
__device__ __forceinline__ float tanh_f(float x) {
  float ax = fabsf(x);
  float e = __expf(-2.0f * ax);
  float t = (1.0f - e) / (1.0f + e);
  return copysignf(t, x);
}

// ---------------------------------------------------------------------------
// f32 tiled GEMM (unchanged from R2): C[M,N] = epi(A[M,K] @ W[N,K]^T).
// ---------------------------------------------------------------------------
template<int EPI, bool RELU>
__global__ __launch_bounds__(256) void gemm_f32(
    const float* __restrict__ A, const float* __restrict__ W,
    const float* __restrict__ bias, const float* __restrict__ R,
    float* __restrict__ C, int M, int N, int K,
    const float* __restrict__ log_s)
{
  const int BM = 64, BN = 64, BK = 16;
  __shared__ float As[BK][BM + 4];
  __shared__ float Ws[BK][BN + 4];
  const int bm = blockIdx.x * BM, bn = blockIdx.y * BN;
  const int t = threadIdx.x;
  const int tx = t & 15, ty = t >> 4;
  const int lm = t >> 2, lk = (t & 3) << 2;

  float acc[4][4] = {};
  const float* Ap = A + (size_t)(bm + lm) * K + lk;
  const float* Wp = W + (size_t)(bn + lm) * K + lk;

  for (int k0 = 0; k0 < K; k0 += BK) {
    float4 av = *reinterpret_cast<const float4*>(Ap + k0);
    float4 wv = *reinterpret_cast<const float4*>(Wp + k0);
    As[lk + 0][lm] = av.x; As[lk + 1][lm] = av.y;
    As[lk + 2][lm] = av.z; As[lk + 3][lm] = av.w;
    Ws[lk + 0][lm] = wv.x; Ws[lk + 1][lm] = wv.y;
    Ws[lk + 2][lm] = wv.z; Ws[lk + 3][lm] = wv.w;
    __syncthreads();
#pragma unroll
    for (int kk = 0; kk < BK; ++kk) {
      float4 a4 = *reinterpret_cast<const float4*>(&As[kk][ty << 2]);
      float4 w4 = *reinterpret_cast<const float4*>(&Ws[kk][tx << 2]);
      float a[4] = {a4.x, a4.y, a4.z, a4.w};
      float w[4] = {w4.x, w4.y, w4.z, w4.w};
#pragma unroll
      for (int i = 0; i < 4; ++i)
#pragma unroll
        for (int jj = 0; jj < 4; ++jj)
          acc[i][jj] = fmaf(a[i], w[jj], acc[i][jj]);
    }
    __syncthreads();
  }

  const int n0 = bn + (tx << 2);
  float b4[4];
#pragma unroll
  for (int jj = 0; jj < 4; ++jj) b4[jj] = bias[n0 + jj];
  float scale = 1.f;
  if (EPI == 1) {
    int chn = n0 / 768;
    float ls = log_s[chn];
    ls = fminf(fmaxf(ls, -10.f), 10.f);
    scale = __expf(-ls);
  }
#pragma unroll
  for (int i = 0; i < 4; ++i) {
    const int m = bm + (ty << 2) + i;
    float vals[4];
    float4 r4;
    if (EPI == 2) r4 = *reinterpret_cast<const float4*>(R + (size_t)m * N + n0);
#pragma unroll
    for (int jj = 0; jj < 4; ++jj) {
      float v = acc[i][jj];
      if (EPI == 1) v *= scale;
      v += b4[jj];
      if (EPI == 2) v += (jj == 0 ? r4.x : jj == 1 ? r4.y : jj == 2 ? r4.z : r4.w);
      if (RELU) v = fmaxf(v, 0.f);
      vals[jj] = v;
    }
    float4 o; o.x = vals[0]; o.y = vals[1]; o.z = vals[2]; o.w = vals[3];
    *reinterpret_cast<float4*>(C + (size_t)m * N + n0) = o;
  }
}

// ---------------------------------------------------------------------------
// LayerNorm over 1024 features (unchanged).
// ---------------------------------------------------------------------------
template<bool ADD>
__global__ __launch_bounds__(256) void ln_kernel(const float* __restrict__ X,
                                                 const float* __restrict__ Yad,
                                                 float* __restrict__ O)
{
  const int row = blockIdx.x, t = threadIdx.x;
  float4 v = reinterpret_cast<const float4*>(X + (size_t)row * NST)[t];
  if (ADD) {
    float4 w = reinterpret_cast<const float4*>(Yad + (size_t)row * NST)[t];
    v.x += w.x; v.y += w.y; v.z += w.z; v.w += w.w;
  }
  float s  = v.x + v.y + v.z + v.w;
  float ss = v.x * v.x + v.y * v.y + v.z * v.z + v.w * v.w;
#pragma unroll
  for (int m = 1; m < 64; m <<= 1) {
    s  += __shfl_xor(s, m, 64);
    ss += __shfl_xor(ss, m, 64);
  }
  __shared__ float ps[4], pss[4];
  const int wv = t >> 6;
  if ((t & 63) == 0) { ps[wv] = s; pss[wv] = ss; }
  __syncthreads();
  s  = ps[0] + ps[1] + ps[2] + ps[3];
  ss = pss[0] + pss[1] + pss[2] + pss[3];
  const float mean = s * (1.f / 1024.f);
  const float var  = ss * (1.f / 1024.f) - mean * mean;
  const float rstd = rsqrtf(var + 1e-5f);
  v.x = (v.x - mean) * rstd; v.y = (v.y - mean) * rstd;
  v.z = (v.z - mean) * rstd; v.w = (v.w - mean) * rstd;
  reinterpret_cast<float4*>(O + (size_t)row * NST)[t] = v;
}

// ---------------------------------------------------------------------------
// ScaleGRU scan, R6C64: grid=4 (1 block/channel/CU), 512 threads (8 waves,
// 2/SIMD). Lane = (slot j>>2, chunk c=j&3). Slot owns units {2s,2s+1}; lane
// holds 6 gate-rows x 64 cols of whh as 192 NAMED f16x2 scalars (R1/R2:
// arrays of f16x2 were demoted to scratch at VGPR_Count=208/128 — named SSA
// values can't be). h is f16 in LDS, chunk-strided 144B so the 4 distinct
// b128 read addrs hit disjoint banks. Column-split reduced via quad_perm DPP
// butterfly (VALU), gates 4-way redundant, one lgkm-only barrier per step
// (double-buffered h; must NOT drain vmcnt — ig prefetch & y stores in flight).
// ---------------------------------------------------------------------------
#define SCAN_BAR() asm volatile("s_waitcnt lgkmcnt(0)\n\ts_barrier" ::: "memory")

#define FOR32(M, P) M(P,0) M(P,1) M(P,2) M(P,3) M(P,4) M(P,5) M(P,6) M(P,7) \
  M(P,8) M(P,9) M(P,10) M(P,11) M(P,12) M(P,13) M(P,14) M(P,15) M(P,16) M(P,17) \
  M(P,18) M(P,19) M(P,20) M(P,21) M(P,22) M(P,23) M(P,24) M(P,25) M(P,26) M(P,27) \
  M(P,28) M(P,29) M(P,30) M(P,31)

#define DECLW(P, k) f16x2 P##k;

#define LWQ(P, q, a, b) { \
  float4 v = *reinterpret_cast<const float4*>(rb + 4 * (q)); \
  P##a = f16x2{(_Float16)v.x, (_Float16)v.y}; \
  P##b = f16x2{(_Float16)v.z, (_Float16)v.w}; }

#define LOADROW(P) \
  LWQ(P,0,0,1)   LWQ(P,1,2,3)   LWQ(P,2,4,5)   LWQ(P,3,6,7) \
  LWQ(P,4,8,9)   LWQ(P,5,10,11) LWQ(P,6,12,13) LWQ(P,7,14,15) \
  LWQ(P,8,16,17) LWQ(P,9,18,19) LWQ(P,10,20,21) LWQ(P,11,22,23) \
  LWQ(P,12,24,25) LWQ(P,13,26,27) LWQ(P,14,28,29) LWQ(P,15,30,31)

// one float4 of h (8 cols = 4 f16x2) x 6 rows = 24 dot2
#define DQ8(Q, A, B, C, D) { \
  float4 hv = hl4[Q]; \
  f16x2 hp0 = __builtin_bit_cast(f16x2, hv.x); \
  f16x2 hp1 = __builtin_bit_cast(f16x2, hv.y); \
  f16x2 hp2 = __builtin_bit_cast(f16x2, hv.z); \
  f16x2 hp3 = __builtin_bit_cast(f16x2, hv.w); \
  s0r = fdot2f(w0r##A, hp0, s0r); s0z = fdot2f(w0z##A, hp0, s0z); s0n = fdot2f(w0n##A, hp0, s0n); \
  s1r = fdot2f(w1r##A, hp0, s1r); s1z = fdot2f(w1z##A, hp0, s1z); s1n = fdot2f(w1n##A, hp0, s1n); \
  s0r = fdot2f(w0r##B, hp1, s0r); s0z = fdot2f(w0z##B, hp1, s0z); s0n = fdot2f(w0n##B, hp1, s0n); \
  s1r = fdot2f(w1r##B, hp1, s1r); s1z = fdot2f(w1z##B, hp1, s1z); s1n = fdot2f(w1n##B, hp1, s1n); \
  s0r = fdot2f(w0r##C, hp2, s0r); s0z = fdot2f(w0z##C, hp2, s0z); s0n = fdot2f(w0n##C, hp2, s0n); \
  s1r = fdot2f(w1r##C, hp2, s1r); s1z = fdot2f(w1z##C, hp2, s1z); s1n = fdot2f(w1n##C, hp2, s1n); \
  s0r = fdot2f(w0r##D, hp3, s0r); s0z = fdot2f(w0z##D, hp3, s0z); s0n = fdot2f(w0n##D, hp3, s0n); \
  s1r = fdot2f(w1r##D, hp3, s1r); s1z = fdot2f(w1z##D, hp3, s1z); s1n = fdot2f(w1n##D, hp3, s1n); }

#define DOT8 \
  DQ8(0,0,1,2,3)     DQ8(1,4,5,6,7)     DQ8(2,8,9,10,11)   DQ8(3,12,13,14,15) \
  DQ8(4,16,17,18,19) DQ8(5,20,21,22,23) DQ8(6,24,25,26,27) DQ8(7,28,29,30,31)

__global__ __launch_bounds__(512, 2) void scan_kernel(
    const float* __restrict__ whh,    // [NCH,768,256] layer slice
    const float* __restrict__ bn_,    // [NCH,256]
    const float* __restrict__ log_s,  // [NCH]
    const float* __restrict__ ig,     // [T, 3072]
    const float* __restrict__ h0,     // [256]
    float* __restrict__ y)            // [T, 1024]
{
  const int ch   = blockIdx.x;
  const int j    = threadIdx.x;
  const int c    = j & 3;       // column chunk: cols [64c, 64c+64)
  const int slot = j >> 2;      // 0..127
  const int u0   = slot * 2, u1 = u0 + 1;
  const float* wc  = whh + (size_t)ch * 768 * 256;
  const float* igc = ig + ch * 768;
  float* yc        = y + ch * GHH;

  FOR32(DECLW, w0r) FOR32(DECLW, w0z) FOR32(DECLW, w0n)
  FOR32(DECLW, w1r) FOR32(DECLW, w1z) FOR32(DECLW, w1n)

  { const float* rb = wc + (size_t)u0 * 256 + 64 * c;          LOADROW(w0r) }
  { const float* rb = wc + (size_t)(u0 + 256) * 256 + 64 * c;  LOADROW(w0z) }
  { const float* rb = wc + (size_t)(u0 + 512) * 256 + 64 * c;  LOADROW(w0n) }
  { const float* rb = wc + (size_t)u1 * 256 + 64 * c;          LOADROW(w1r) }
  { const float* rb = wc + (size_t)(u1 + 256) * 256 + 64 * c;  LOADROW(w1z) }
  { const float* rb = wc + (size_t)(u1 + 512) * 256 + 64 * c;  LOADROW(w1n) }

  const float bn0 = bn_[ch * GHH + u0], bn1 = bn_[ch * GHH + u1];
  float ls = log_s[ch];
  ls = fminf(fmaxf(ls, -10.f), 10.f);
  const float inv_s = __expf(-ls);
  float h0r = h0[u0], h1r = h0[u1];

  // h buffers: 4 chunks x 144B (128B data + 16B pad -> read banks 4c+4q, disjoint)
  __shared__ __align__(16) unsigned char hsh[2][576];
  const int wb = ((u0 >> 6) * 144) + ((u0 & 63) * 2);
  if (c == 0)
    *reinterpret_cast<f16x2*>(&hsh[0][wb]) = f16x2{(_Float16)h0r, (_Float16)h1r};
  SCAN_BAR();

  // 2-deep ig prefetch: i* = ig[t], jj* = ig[t+1]
  float i0r, i0z, i0n, i1r, i1z, i1n, q0r, q0z, q0n, q1r, q1z, q1n;
  {
    const float* p0 = igc;
    i0r = p0[u0]; i0z = p0[256 + u0]; i0n = p0[512 + u0];
    i1r = p0[u1]; i1z = p0[256 + u1]; i1n = p0[512 + u1];
    const float* p1 = igc + LD_IG;
    q0r = p1[u0]; q0z = p1[256 + u0]; q0n = p1[512 + u0];
    q1r = p1[u1]; q1z = p1[256 + u1]; q1n = p1[512 + u1];
  }

  for (int t = 0; t < T_SEQ; ++t) {
    float p0r = 0.f, p0z = 0.f, p0n = 0.f, p1r = 0.f, p1z = 0.f, p1n = 0.f;
    if (t + 2 < T_SEQ) {
      const float* p = igc + (size_t)(t + 2) * LD_IG;
      p0r = p[u0]; p0z = p[256 + u0]; p0n = p[512 + u0];
      p1r = p[u1]; p1z = p[256 + u1]; p1n = p[512 + u1];
    }
    float s0r = 0.f, s0z = 0.f, s0n = 0.f, s1r = 0.f, s1z = 0.f, s1n = 0.f;
    const float4* hl4 =
        reinterpret_cast<const float4*>(&hsh[t & 1][c * 144]);
    DOT8
    // reduce across the 4 chunk-lanes (one quad) on the VALU pipe
    s0r = dpp_xor_add<0xB1>(s0r); s0z = dpp_xor_add<0xB1>(s0z); s0n = dpp_xor_add<0xB1>(s0n);
    s1r = dpp_xor_add<0xB1>(s1r); s1z = dpp_xor_add<0xB1>(s1z); s1n = dpp_xor_add<0xB1>(s1n);
    s0r = dpp_xor_add<0x4E>(s0r); s0z = dpp_xor_add<0x4E>(s0z); s0n = dpp_xor_add<0x4E>(s0n);
    s1r = dpp_xor_add<0x4E>(s1r); s1z = dpp_xor_add<0x4E>(s1z); s1n = dpp_xor_add<0x4E>(s1n);
    // gates (computed redundantly in all 4 chunk-lanes; stores masked to c==0)
    {
      const float r = sigmoid_f(i0r + s0r);
      const float z = sigmoid_f(i0z + s0z);
      const float n = tanh_f(i0n + r * (s0n + bn0));
      const float hnew = n + z * (h0r - n);
      h0r = (hnew - h0r) * inv_s + h0r;
    }
    {
      const float r = sigmoid_f(i1r + s1r);
      const float z = sigmoid_f(i1z + s1z);
      const float n = tanh_f(i1n + r * (s1n + bn1));
      const float hnew = n + z * (h1r - n);
      h1r = (hnew - h1r) * inv_s + h1r;
    }
    if (c == 0) {
      *reinterpret_cast<float2*>(yc + (size_t)t * NST + u0) = float2{h0r, h1r};
      *reinterpret_cast<f16x2*>(&hsh[(t + 1) & 1][wb]) =
          f16x2{(_Float16)h0r, (_Float16)h1r};
    }
    SCAN_BAR();
    i0r = q0r; i0z = q0z; i0n = q0n; i1r = q1r; i1z = q1z; i1n = q1n;
    q0r = p0r; q0z = p0z; q0n = p0n; q1r = p1r; q1z = p1z; q1n = p1n;
  }
}

// ---------------------------------------------------------------------------
// Classifier second GEMM: N=10, K=1024. One block per row (unchanged).
// ---------------------------------------------------------------------------
__global__ __launch_bounds__(256) void gemv_cls(const float* __restrict__ A,
                                                const float* __restrict__ W,
                                                const float* __restrict__ b,
                                                float* __restrict__ out)
{
  const int m = blockIdx.x, t = threadIdx.x;
  float4 a = reinterpret_cast<const float4*>(A + (size_t)m * NST)[t];
  float p[10];
#pragma unroll
  for (int n = 0; n < 10; ++n) {
    float4 w = reinterpret_cast<const float4*>(W + (size_t)n * NST)[t];
    p[n] = a.x * w.x + a.y * w.y + a.z * w.z + a.w * w.w;
  }
#pragma unroll
  for (int n = 0; n < 10; ++n)
#pragma unroll
    for (int msk = 1; msk < 64; msk <<= 1) p[n] += __shfl_xor(p[n], msk, 64);
  __shared__ float red[4][10];
  const int wv = t >> 6;
  if ((t & 63) == 0) {
#pragma unroll
    for (int n = 0; n < 10; ++n) red[wv][n] = p[n];
  }
  __syncthreads();
  if (t < 10) {
    float v = red[0][t] + red[1][t] + red[2][t] + red[3][t] + b[t];
    out[(size_t)m * 10 + t] = v;
  }
}

// ---------------------------------------------------------------------------
extern "C" void kernel_launch(void* const* d_in, const int* in_sizes, int n_in,
                              void* d_out, int out_size, void* d_ws, size_t ws_size,
                              hipStream_t stream) {
  const float* inputs = (const float*)d_in[0];
  const float* h0     = (const float*)d_in[1];
  // d_in[2] = yinit_guess: unused (exact solution independent of it)
  const float* enc_w1 = (const float*)d_in[3];
  const float* enc_b1 = (const float*)d_in[4];
  const float* enc_w2 = (const float*)d_in[5];
  const float* enc_b2 = (const float*)d_in[6];
  const float* gwih   = (const float*)d_in[7];   // [3,4,768,1024]
  const float* gwhh   = (const float*)d_in[8];   // [3,4,768,256]
  const float* gb     = (const float*)d_in[9];   // [3,4,768]
  const float* gbn    = (const float*)d_in[10];  // [3,4,256]
  const float* gls    = (const float*)d_in[11];  // [3,4,1]
  const float* mw1    = (const float*)d_in[12];
  const float* mb1    = (const float*)d_in[13];
  const float* mw2    = (const float*)d_in[14];
  const float* mb2    = (const float*)d_in[15];
  const float* cw1    = (const float*)d_in[16];
  const float* cb1    = (const float*)d_in[17];
  const float* cw2    = (const float*)d_in[18];
  const float* cb2    = (const float*)d_in[19];
  float* out = (float*)d_out;

  char* ws = (char*)d_ws;
  float* bufA = (float*)ws;                          // [8192,1024] 33.5MB
  float* bufB = (float*)(ws + (size_t)33554432);     // [8192,1024] 33.5MB
  float* bufG = (float*)(ws + (size_t)67108864);     // [8192,3072] 100.7MB (ig / mlp hidden)

  const dim3 blk(256);
  const dim3 gemm_1024(8192 / 64, 1024 / 64);
  const dim3 gemm_3072(8192 / 64, 3072 / 64);

  // encoder
  gemm_f32<0, true ><<<gemm_1024, blk, 0, stream>>>(inputs, enc_w1, enc_b1, nullptr,
                                                    bufG, 8192, 1024, 128, nullptr);
  gemm_f32<0, false><<<gemm_1024, blk, 0, stream>>>(bufG, enc_w2, enc_b2, nullptr,
                                                    bufA, 8192, 1024, 1024, nullptr);
  float* x  = bufA;
  float* xb = bufB;
  for (int i = 0; i < 3; ++i) {
    ln_kernel<false><<<dim3(8192), blk, 0, stream>>>(x, nullptr, xb);
    gemm_f32<1, false><<<gemm_3072, blk, 0, stream>>>(xb, gwih + (size_t)i * 4 * 768 * 1024,
                                                      gb + (size_t)i * 3072, nullptr,
                                                      bufG, 8192, 3072, 1024,
                                                      gls + (size_t)i * 4);
    scan_kernel<<<dim3(4), dim3(512), 0, stream>>>(gwhh + (size_t)i * 4 * 768 * 256,
                                                   gbn + (size_t)i * 1024,
                                                   gls + (size_t)i * 4,
                                                   bufG, h0, x);
    ln_kernel<true><<<dim3(8192), blk, 0, stream>>>(x, xb, x);
    gemm_f32<0, true ><<<gemm_1024, blk, 0, stream>>>(x, mw1 + (size_t)i * 1048576,
                                                      mb1 + (size_t)i * 1024, nullptr,
                                                      bufG, 8192, 1024, 1024, nullptr);
    gemm_f32<2, false><<<gemm_1024, blk, 0, stream>>>(bufG, mw2 + (size_t)i * 1048576,
                                                      mb2 + (size_t)i * 1024, x,
                                                      xb, 8192, 1024, 1024, nullptr);
    float* tmp = x; x = xb; xb = tmp;
  }
  // classifier
  gemm_f32<0, true><<<gemm_1024, blk, 0, stream>>>(x, cw1, cb1, nullptr,
                                                   bufG, 8192, 1024, 1024, nullptr);
  gemv_cls<<<dim3(8192), blk, 0, stream>>>(bufG, cw2, cb2, out);
}

// Round 4
// 38224.155 us; speedup vs baseline: 1.0027x; 1.0027x over previous
//
#include <hip/hip_runtime.h>

// MultiScaleGRU: T=8192, NINP=128, NSTATE=1024, NCH=4, GH=256, NLAYER=3, NCLASS=10
#define T_SEQ 8192
#define NST   1024
#define GHH   256
#define LD_IG 3072   // 4 channels * 768 ig columns

typedef _Float16 f16x2 __attribute__((ext_vector_type(2)));

#if defined(__has_builtin)
#if __has_builtin(__builtin_amdgcn_fdot2)
#define HAVE_FDOT2 1
#endif
#endif

__device__ __forceinline__ float fdot2f(f16x2 a, f16x2 b, float c) {
#ifdef HAVE_FDOT2
  return __builtin_amdgcn_fdot2(a, b, c, false);
#else
  float d;
  asm("v_dot2_f32_f16 %0, %1, %2, %3" : "=v"(d) : "v"(a), "v"(b), "v"(c));
  return d;
#endif
}

// quad-lane XOR butterfly add via DPP (VALU pipe — keeps reduce off the LDS pipe)
template<int CTRL>
__device__ __forceinline__ float dpp_xor_add(float x) {
#if defined(__has_builtin) && __has_builtin(__builtin_amdgcn_update_dpp)
  int s = __builtin_amdgcn_update_dpp(0, __builtin_bit_cast(int, x), CTRL, 0xF, 0xF, true);
  return x + __builtin_bit_cast(float, s);
#else
  return x + __shfl_xor(x, (CTRL == 0xB1) ? 1 : 2, 64);
#endif
}

__device__ __forceinline__ float sigmoid_f(float x) {
  return 1.0f / (1.0f + __expf(-x));
}
__device__ __forceinline__ float tanh_f(float x) {
  float ax = fabsf(x);
  float e = __expf(-2.0f * ax);
  float t = (1.0f - e) / (1.0f + e);
  return copysignf(t, x);
}

// ---------------------------------------------------------------------------
// f32 tiled GEMM (unchanged): C[M,N] = epi(A[M,K] @ W[N,K]^T).
// ---------------------------------------------------------------------------
template<int EPI, bool RELU>
__global__ __launch_bounds__(256) void gemm_f32(
    const float* __restrict__ A, const float* __restrict__ W,
    const float* __restrict__ bias, const float* __restrict__ R,
    float* __restrict__ C, int M, int N, int K,
    const float* __restrict__ log_s)
{
  const int BM = 64, BN = 64, BK = 16;
  __shared__ float As[BK][BM + 4];
  __shared__ float Ws[BK][BN + 4];
  const int bm = blockIdx.x * BM, bn = blockIdx.y * BN;
  const int t = threadIdx.x;
  const int tx = t & 15, ty = t >> 4;
  const int lm = t >> 2, lk = (t & 3) << 2;

  float acc[4][4] = {};
  const float* Ap = A + (size_t)(bm + lm) * K + lk;
  const float* Wp = W + (size_t)(bn + lm) * K + lk;

  for (int k0 = 0; k0 < K; k0 += BK) {
    float4 av = *reinterpret_cast<const float4*>(Ap + k0);
    float4 wv = *reinterpret_cast<const float4*>(Wp + k0);
    As[lk + 0][lm] = av.x; As[lk + 1][lm] = av.y;
    As[lk + 2][lm] = av.z; As[lk + 3][lm] = av.w;
    Ws[lk + 0][lm] = wv.x; Ws[lk + 1][lm] = wv.y;
    Ws[lk + 2][lm] = wv.z; Ws[lk + 3][lm] = wv.w;
    __syncthreads();
#pragma unroll
    for (int kk = 0; kk < BK; ++kk) {
      float4 a4 = *reinterpret_cast<const float4*>(&As[kk][ty << 2]);
      float4 w4 = *reinterpret_cast<const float4*>(&Ws[kk][tx << 2]);
      float a[4] = {a4.x, a4.y, a4.z, a4.w};
      float w[4] = {w4.x, w4.y, w4.z, w4.w};
#pragma unroll
      for (int i = 0; i < 4; ++i)
#pragma unroll
        for (int jj = 0; jj < 4; ++jj)
          acc[i][jj] = fmaf(a[i], w[jj], acc[i][jj]);
    }
    __syncthreads();
  }

  const int n0 = bn + (tx << 2);
  float b4[4];
#pragma unroll
  for (int jj = 0; jj < 4; ++jj) b4[jj] = bias[n0 + jj];
  float scale = 1.f;
  if (EPI == 1) {
    int chn = n0 / 768;
    float ls = log_s[chn];
    ls = fminf(fmaxf(ls, -10.f), 10.f);
    scale = __expf(-ls);
  }
#pragma unroll
  for (int i = 0; i < 4; ++i) {
    const int m = bm + (ty << 2) + i;
    float vals[4];
    float4 r4;
    if (EPI == 2) r4 = *reinterpret_cast<const float4*>(R + (size_t)m * N + n0);
#pragma unroll
    for (int jj = 0; jj < 4; ++jj) {
      float v = acc[i][jj];
      if (EPI == 1) v *= scale;
      v += b4[jj];
      if (EPI == 2) v += (jj == 0 ? r4.x : jj == 1 ? r4.y : jj == 2 ? r4.z : r4.w);
      if (RELU) v = fmaxf(v, 0.f);
      vals[jj] = v;
    }
    float4 o; o.x = vals[0]; o.y = vals[1]; o.z = vals[2]; o.w = vals[3];
    *reinterpret_cast<float4*>(C + (size_t)m * N + n0) = o;
  }
}

// ---------------------------------------------------------------------------
// LayerNorm over 1024 features (unchanged).
// ---------------------------------------------------------------------------
template<bool ADD>
__global__ __launch_bounds__(256) void ln_kernel(const float* __restrict__ X,
                                                 const float* __restrict__ Yad,
                                                 float* __restrict__ O)
{
  const int row = blockIdx.x, t = threadIdx.x;
  float4 v = reinterpret_cast<const float4*>(X + (size_t)row * NST)[t];
  if (ADD) {
    float4 w = reinterpret_cast<const float4*>(Yad + (size_t)row * NST)[t];
    v.x += w.x; v.y += w.y; v.z += w.z; v.w += w.w;
  }
  float s  = v.x + v.y + v.z + v.w;
  float ss = v.x * v.x + v.y * v.y + v.z * v.z + v.w * v.w;
#pragma unroll
  for (int m = 1; m < 64; m <<= 1) {
    s  += __shfl_xor(s, m, 64);
    ss += __shfl_xor(ss, m, 64);
  }
  __shared__ float ps[4], pss[4];
  const int wv = t >> 6;
  if ((t & 63) == 0) { ps[wv] = s; pss[wv] = ss; }
  __syncthreads();
  s  = ps[0] + ps[1] + ps[2] + ps[3];
  ss = pss[0] + pss[1] + pss[2] + pss[3];
  const float mean = s * (1.f / 1024.f);
  const float var  = ss * (1.f / 1024.f) - mean * mean;
  const float rstd = rsqrtf(var + 1e-5f);
  v.x = (v.x - mean) * rstd; v.y = (v.y - mean) * rstd;
  v.z = (v.z - mean) * rstd; v.w = (v.w - mean) * rstd;
  reinterpret_cast<float4*>(O + (size_t)row * NST)[t] = v;
}

// ---------------------------------------------------------------------------
// ScaleGRU scan, R6C64 (structure identical to R3). ONE change: occupancy is
// PINNED via amdgpu_waves_per_eu(2,2) instead of __launch_bounds__(512,2).
// R2/R3 both allocated exactly 128 VGPR = 512-slot SIMD file / 4 waves — the
// backend's default 4-waves/EU occupancy target — and spilled ~100 regs of
// weights to scratch (the 9-11ms is scratch streaming, not compute).
// Pinning min=max=2 waves/EU gives a hard 256-VGPR budget; live set is
// ~235 (192 weight f16x2 + 18 ig prefetch + ~25 misc).
// ---------------------------------------------------------------------------
#define SCAN_BAR() asm volatile("s_waitcnt lgkmcnt(0)\n\ts_barrier" ::: "memory")

#define FOR32(M, P) M(P,0) M(P,1) M(P,2) M(P,3) M(P,4) M(P,5) M(P,6) M(P,7) \
  M(P,8) M(P,9) M(P,10) M(P,11) M(P,12) M(P,13) M(P,14) M(P,15) M(P,16) M(P,17) \
  M(P,18) M(P,19) M(P,20) M(P,21) M(P,22) M(P,23) M(P,24) M(P,25) M(P,26) M(P,27) \
  M(P,28) M(P,29) M(P,30) M(P,31)

#define DECLW(P, k) f16x2 P##k;

#define LWQ(P, q, a, b) { \
  float4 v = *reinterpret_cast<const float4*>(rb + 4 * (q)); \
  P##a = f16x2{(_Float16)v.x, (_Float16)v.y}; \
  P##b = f16x2{(_Float16)v.z, (_Float16)v.w}; }

#define LOADROW(P) \
  LWQ(P,0,0,1)   LWQ(P,1,2,3)   LWQ(P,2,4,5)   LWQ(P,3,6,7) \
  LWQ(P,4,8,9)   LWQ(P,5,10,11) LWQ(P,6,12,13) LWQ(P,7,14,15) \
  LWQ(P,8,16,17) LWQ(P,9,18,19) LWQ(P,10,20,21) LWQ(P,11,22,23) \
  LWQ(P,12,24,25) LWQ(P,13,26,27) LWQ(P,14,28,29) LWQ(P,15,30,31)

// one float4 of h (8 cols = 4 f16x2) x 6 rows = 24 dot2
#define DQ8(Q, A, B, C, D) { \
  float4 hv = hl4[Q]; \
  f16x2 hp0 = __builtin_bit_cast(f16x2, hv.x); \
  f16x2 hp1 = __builtin_bit_cast(f16x2, hv.y); \
  f16x2 hp2 = __builtin_bit_cast(f16x2, hv.z); \
  f16x2 hp3 = __builtin_bit_cast(f16x2, hv.w); \
  s0r = fdot2f(w0r##A, hp0, s0r); s0z = fdot2f(w0z##A, hp0, s0z); s0n = fdot2f(w0n##A, hp0, s0n); \
  s1r = fdot2f(w1r##A, hp0, s1r); s1z = fdot2f(w1z##A, hp0, s1z); s1n = fdot2f(w1n##A, hp0, s1n); \
  s0r = fdot2f(w0r##B, hp1, s0r); s0z = fdot2f(w0z##B, hp1, s0z); s0n = fdot2f(w0n##B, hp1, s0n); \
  s1r = fdot2f(w1r##B, hp1, s1r); s1z = fdot2f(w1z##B, hp1, s1z); s1n = fdot2f(w1n##B, hp1, s1n); \
  s0r = fdot2f(w0r##C, hp2, s0r); s0z = fdot2f(w0z##C, hp2, s0z); s0n = fdot2f(w0n##C, hp2, s0n); \
  s1r = fdot2f(w1r##C, hp2, s1r); s1z = fdot2f(w1z##C, hp2, s1z); s1n = fdot2f(w1n##C, hp2, s1n); \
  s0r = fdot2f(w0r##D, hp3, s0r); s0z = fdot2f(w0z##D, hp3, s0z); s0n = fdot2f(w0n##D, hp3, s0n); \
  s1r = fdot2f(w1r##D, hp3, s1r); s1z = fdot2f(w1z##D, hp3, s1z); s1n = fdot2f(w1n##D, hp3, s1n); }

#define DOT8 \
  DQ8(0,0,1,2,3)     DQ8(1,4,5,6,7)     DQ8(2,8,9,10,11)   DQ8(3,12,13,14,15) \
  DQ8(4,16,17,18,19) DQ8(5,20,21,22,23) DQ8(6,24,25,26,27) DQ8(7,28,29,30,31)

__global__ __attribute__((amdgpu_flat_work_group_size(512, 512),
                          amdgpu_waves_per_eu(2, 2)))
void scan_kernel(
    const float* __restrict__ whh,    // [NCH,768,256] layer slice
    const float* __restrict__ bn_,    // [NCH,256]
    const float* __restrict__ log_s,  // [NCH]
    const float* __restrict__ ig,     // [T, 3072]
    const float* __restrict__ h0,     // [256]
    float* __restrict__ y)            // [T, 1024]
{
  const int ch   = blockIdx.x;
  const int j    = threadIdx.x;
  const int c    = j & 3;       // column chunk: cols [64c, 64c+64)
  const int slot = j >> 2;      // 0..127
  const int u0   = slot * 2, u1 = u0 + 1;
  const float* wc  = whh + (size_t)ch * 768 * 256;
  const float* igc = ig + ch * 768;
  float* yc        = y + ch * GHH;

  FOR32(DECLW, w0r) FOR32(DECLW, w0z) FOR32(DECLW, w0n)
  FOR32(DECLW, w1r) FOR32(DECLW, w1z) FOR32(DECLW, w1n)

  { const float* rb = wc + (size_t)u0 * 256 + 64 * c;          LOADROW(w0r) }
  { const float* rb = wc + (size_t)(u0 + 256) * 256 + 64 * c;  LOADROW(w0z) }
  { const float* rb = wc + (size_t)(u0 + 512) * 256 + 64 * c;  LOADROW(w0n) }
  { const float* rb = wc + (size_t)u1 * 256 + 64 * c;          LOADROW(w1r) }
  { const float* rb = wc + (size_t)(u1 + 256) * 256 + 64 * c;  LOADROW(w1z) }
  { const float* rb = wc + (size_t)(u1 + 512) * 256 + 64 * c;  LOADROW(w1n) }

  const float bn0 = bn_[ch * GHH + u0], bn1 = bn_[ch * GHH + u1];
  float ls = log_s[ch];
  ls = fminf(fmaxf(ls, -10.f), 10.f);
  const float inv_s = __expf(-ls);
  float h0r = h0[u0], h1r = h0[u1];

  // h buffers: 4 chunks x 144B (128B data + 16B pad -> read banks disjoint)
  __shared__ __align__(16) unsigned char hsh[2][576];
  const int wb = ((u0 >> 6) * 144) + ((u0 & 63) * 2);
  if (c == 0)
    *reinterpret_cast<f16x2*>(&hsh[0][wb]) = f16x2{(_Float16)h0r, (_Float16)h1r};
  SCAN_BAR();

  // 2-deep ig prefetch: i* = ig[t], q* = ig[t+1]
  float i0r, i0z, i0n, i1r, i1z, i1n, q0r, q0z, q0n, q1r, q1z, q1n;
  {
    const float* p0 = igc;
    i0r = p0[u0]; i0z = p0[256 + u0]; i0n = p0[512 + u0];
    i1r = p0[u1]; i1z = p0[256 + u1]; i1n = p0[512 + u1];
    const float* p1 = igc + LD_IG;
    q0r = p1[u0]; q0z = p1[256 + u0]; q0n = p1[512 + u0];
    q1r = p1[u1]; q1z = p1[256 + u1]; q1n = p1[512 + u1];
  }

  for (int t = 0; t < T_SEQ; ++t) {
    float p0r = 0.f, p0z = 0.f, p0n = 0.f, p1r = 0.f, p1z = 0.f, p1n = 0.f;
    if (t + 2 < T_SEQ) {
      const float* p = igc + (size_t)(t + 2) * LD_IG;
      p0r = p[u0]; p0z = p[256 + u0]; p0n = p[512 + u0];
      p1r = p[u1]; p1z = p[256 + u1]; p1n = p[512 + u1];
    }
    float s0r = 0.f, s0z = 0.f, s0n = 0.f, s1r = 0.f, s1z = 0.f, s1n = 0.f;
    const float4* hl4 =
        reinterpret_cast<const float4*>(&hsh[t & 1][c * 144]);
    DOT8
    // reduce across the 4 chunk-lanes (one quad) on the VALU pipe
    s0r = dpp_xor_add<0xB1>(s0r); s0z = dpp_xor_add<0xB1>(s0z); s0n = dpp_xor_add<0xB1>(s0n);
    s1r = dpp_xor_add<0xB1>(s1r); s1z = dpp_xor_add<0xB1>(s1z); s1n = dpp_xor_add<0xB1>(s1n);
    s0r = dpp_xor_add<0x4E>(s0r); s0z = dpp_xor_add<0x4E>(s0z); s0n = dpp_xor_add<0x4E>(s0n);
    s1r = dpp_xor_add<0x4E>(s1r); s1z = dpp_xor_add<0x4E>(s1z); s1n = dpp_xor_add<0x4E>(s1n);
    // gates (computed redundantly in all 4 chunk-lanes; stores masked to c==0)
    {
      const float r = sigmoid_f(i0r + s0r);
      const float z = sigmoid_f(i0z + s0z);
      const float n = tanh_f(i0n + r * (s0n + bn0));
      const float hnew = n + z * (h0r - n);
      h0r = (hnew - h0r) * inv_s + h0r;
    }
    {
      const float r = sigmoid_f(i1r + s1r);
      const float z = sigmoid_f(i1z + s1z);
      const float n = tanh_f(i1n + r * (s1n + bn1));
      const float hnew = n + z * (h1r - n);
      h1r = (hnew - h1r) * inv_s + h1r;
    }
    if (c == 0) {
      *reinterpret_cast<float2*>(yc + (size_t)t * NST + u0) = float2{h0r, h1r};
      *reinterpret_cast<f16x2*>(&hsh[(t + 1) & 1][wb]) =
          f16x2{(_Float16)h0r, (_Float16)h1r};
    }
    SCAN_BAR();
    i0r = q0r; i0z = q0z; i0n = q0n; i1r = q1r; i1z = q1z; i1n = q1n;
    q0r = p0r; q0z = p0z; q0n = p0n; q1r = p1r; q1z = p1z; q1n = p1n;
  }
}

// ---------------------------------------------------------------------------
// Classifier second GEMM: N=10, K=1024. One block per row (unchanged).
// ---------------------------------------------------------------------------
__global__ __launch_bounds__(256) void gemv_cls(const float* __restrict__ A,
                                                const float* __restrict__ W,
                                                const float* __restrict__ b,
                                                float* __restrict__ out)
{
  const int m = blockIdx.x, t = threadIdx.x;
  float4 a = reinterpret_cast<const float4*>(A + (size_t)m * NST)[t];
  float p[10];
#pragma unroll
  for (int n = 0; n < 10; ++n) {
    float4 w = reinterpret_cast<const float4*>(W + (size_t)n * NST)[t];
    p[n] = a.x * w.x + a.y * w.y + a.z * w.z + a.w * w.w;
  }
#pragma unroll
  for (int n = 0; n < 10; ++n)
#pragma unroll
    for (int msk = 1; msk < 64; msk <<= 1) p[n] += __shfl_xor(p[n], msk, 64);
  __shared__ float red[4][10];
  const int wv = t >> 6;
  if ((t & 63) == 0) {
#pragma unroll
    for (int n = 0; n < 10; ++n) red[wv][n] = p[n];
  }
  __syncthreads();
  if (t < 10) {
    float v = red[0][t] + red[1][t] + red[2][t] + red[3][t] + b[t];
    out[(size_t)m * 10 + t] = v;
  }
}

// ---------------------------------------------------------------------------
extern "C" void kernel_launch(void* const* d_in, const int* in_sizes, int n_in,
                              void* d_out, int out_size, void* d_ws, size_t ws_size,
                              hipStream_t stream) {
  const float* inputs = (const float*)d_in[0];
  const float* h0     = (const float*)d_in[1];
  // d_in[2] = yinit_guess: unused (exact solution independent of it)
  const float* enc_w1 = (const float*)d_in[3];
  const float* enc_b1 = (const float*)d_in[4];
  const float* enc_w2 = (const float*)d_in[5];
  const float* enc_b2 = (const float*)d_in[6];
  const float* gwih   = (const float*)d_in[7];   // [3,4,768,1024]
  const float* gwhh   = (const float*)d_in[8];   // [3,4,768,256]
  const float* gb     = (const float*)d_in[9];   // [3,4,768]
  const float* gbn    = (const float*)d_in[10];  // [3,4,256]
  const float* gls    = (const float*)d_in[11];  // [3,4,1]
  const float* mw1    = (const float*)d_in[12];
  const float* mb1    = (const float*)d_in[13];
  const float* mw2    = (const float*)d_in[14];
  const float* mb2    = (const float*)d_in[15];
  const float* cw1    = (const float*)d_in[16];
  const float* cb1    = (const float*)d_in[17];
  const float* cw2    = (const float*)d_in[18];
  const float* cb2    = (const float*)d_in[19];
  float* out = (float*)d_out;

  char* ws = (char*)d_ws;
  float* bufA = (float*)ws;                          // [8192,1024] 33.5MB
  float* bufB = (float*)(ws + (size_t)33554432);     // [8192,1024] 33.5MB
  float* bufG = (float*)(ws + (size_t)67108864);     // [8192,3072] 100.7MB (ig / mlp hidden)

  const dim3 blk(256);
  const dim3 gemm_1024(8192 / 64, 1024 / 64);
  const dim3 gemm_3072(8192 / 64, 3072 / 64);

  // encoder
  gemm_f32<0, true ><<<gemm_1024, blk, 0, stream>>>(inputs, enc_w1, enc_b1, nullptr,
                                                    bufG, 8192, 1024, 128, nullptr);
  gemm_f32<0, false><<<gemm_1024, blk, 0, stream>>>(bufG, enc_w2, enc_b2, nullptr,
                                                    bufA, 8192, 1024, 1024, nullptr);
  float* x  = bufA;
  float* xb = bufB;
  for (int i = 0; i < 3; ++i) {
    ln_kernel<false><<<dim3(8192), blk, 0, stream>>>(x, nullptr, xb);
    gemm_f32<1, false><<<gemm_3072, blk, 0, stream>>>(xb, gwih + (size_t)i * 4 * 768 * 1024,
                                                      gb + (size_t)i * 3072, nullptr,
                                                      bufG, 8192, 3072, 1024,
                                                      gls + (size_t)i * 4);
    scan_kernel<<<dim3(4), dim3(512), 0, stream>>>(gwhh + (size_t)i * 4 * 768 * 256,
                                                   gbn + (size_t)i * 1024,
                                                   gls + (size_t)i * 4,
                                                   bufG, h0, x);
    ln_kernel<true><<<dim3(8192), blk, 0, stream>>>(x, xb, x);
    gemm_f32<0, true ><<<gemm_1024, blk, 0, stream>>>(x, mw1 + (size_t)i * 1048576,
                                                      mb1 + (size_t)i * 1024, nullptr,
                                                      bufG, 8192, 1024, 1024, nullptr);
    gemm_f32<2, false><<<gemm_1024, blk, 0, stream>>>(bufG, mw2 + (size_t)i * 1048576,
                                                      mb2 + (size_t)i * 1024, x,
                                                      xb, 8192, 1024, 1024, nullptr);
    float* tmp = x; x = xb; xb = tmp;
  }
  // classifier
  gemm_f32<0, true><<<gemm_1024, blk, 0, stream>>>(x, cw1, cb1, nullptr,
                                                   bufG, 8192, 1024, 1024, nullptr);
  gemv_cls<<<dim3(8192), blk, 0, stream>>>(bufG, cw2, cb2, out);
}

// Round 5
// 37104.916 us; speedup vs baseline: 1.0329x; 1.0302x over previous
//
#include <hip/hip_runtime.h>

// MultiScaleGRU: T=8192, NINP=128, NSTATE=1024, NCH=4, GH=256, NLAYER=3, NCLASS=10
#define T_SEQ 8192
#define NST   1024
#define GHH   256
#define LD_IG 3072        // 4 channels * 768 ig columns
#define GW_OFF 167772160  // byte offset of f16 weight cache in ws (after bufG)

typedef _Float16 f16x2 __attribute__((ext_vector_type(2)));

#if defined(__has_builtin)
#if __has_builtin(__builtin_amdgcn_fdot2)
#define HAVE_FDOT2 1
#endif
#endif

__device__ __forceinline__ float fdot2f(f16x2 a, f16x2 b, float c) {
#ifdef HAVE_FDOT2
  return __builtin_amdgcn_fdot2(a, b, c, false);
#else
  float d;
  asm("v_dot2_f32_f16 %0, %1, %2, %3" : "=v"(d) : "v"(a), "v"(b), "v"(c));
  return d;
#endif
}

// quad-lane XOR butterfly add via DPP (VALU pipe)
template<int CTRL>
__device__ __forceinline__ float dpp_xor_add(float x) {
#if defined(__has_builtin) && __has_builtin(__builtin_amdgcn_update_dpp)
  int s = __builtin_amdgcn_update_dpp(0, __builtin_bit_cast(int, x), CTRL, 0xF, 0xF, true);
  return x + __builtin_bit_cast(float, s);
#else
  return x + __shfl_xor(x, (CTRL == 0xB1) ? 1 : 2, 64);
#endif
}

__device__ __forceinline__ float sigmoid_f(float x) {
  return 1.0f / (1.0f + __expf(-x));
}
__device__ __forceinline__ float tanh_f(float x) {
  float ax = fabsf(x);
  float e = __expf(-2.0f * ax);
  float t = (1.0f - e) / (1.0f + e);
  return copysignf(t, x);
}

// ---------------------------------------------------------------------------
// Prep: convert whh [3,4,768,256] f32 -> f16x2 cache laid out so that scan
// thread j's 96 weight pairs arrive via 24 coalesced dwordx4 loads with NO
// in-kernel conversion (R1-R4: cvt+transient pressure made the allocator
// spill the whole weight class; loads that land directly in the final regs
// keep peak pressure == final footprint).
// Layout: [lc=l*4+ch][q 0..23][jj 0..1023] x 16B; element (q,jj,e) = weight
// flat f=4q+e of thread jj: row r=f>>5 (r/z/n), pair k=f&31, unit u=jj>>2,
// chunk c=jj&3 -> whh[lc][r*256+u][c*64 + 2k, 2k+1].
// ---------------------------------------------------------------------------
__global__ __launch_bounds__(256) void prep_whh(const float* __restrict__ whh,
                                                f16x2* __restrict__ wsw)
{
  const int idx = blockIdx.x * 256 + threadIdx.x;   // 0 .. 294911
  const int jj = idx & 1023;
  const int q  = (idx >> 10) % 24;
  const int lc = idx / (24 * 1024);
  const int u = jj >> 2, c = jj & 3;
  const int r = q >> 3, kb = (q & 7) * 4;           // pairs kb..kb+3
  const float* src = whh + (((size_t)lc * 768 + r * 256 + u) * 256) + c * 64 + 2 * kb;
  float4 a = *reinterpret_cast<const float4*>(src);
  float4 b = *reinterpret_cast<const float4*>(src + 4);
  f16x2* dst = wsw + (size_t)idx * 4;
  dst[0] = f16x2{(_Float16)a.x, (_Float16)a.y};
  dst[1] = f16x2{(_Float16)a.z, (_Float16)a.w};
  dst[2] = f16x2{(_Float16)b.x, (_Float16)b.y};
  dst[3] = f16x2{(_Float16)b.z, (_Float16)b.w};
}

// ---------------------------------------------------------------------------
// f32 tiled GEMM (unchanged): C[M,N] = epi(A[M,K] @ W[N,K]^T).
// ---------------------------------------------------------------------------
template<int EPI, bool RELU>
__global__ __launch_bounds__(256) void gemm_f32(
    const float* __restrict__ A, const float* __restrict__ W,
    const float* __restrict__ bias, const float* __restrict__ R,
    float* __restrict__ C, int M, int N, int K,
    const float* __restrict__ log_s)
{
  const int BM = 64, BN = 64, BK = 16;
  __shared__ float As[BK][BM + 4];
  __shared__ float Ws[BK][BN + 4];
  const int bm = blockIdx.x * BM, bn = blockIdx.y * BN;
  const int t = threadIdx.x;
  const int tx = t & 15, ty = t >> 4;
  const int lm = t >> 2, lk = (t & 3) << 2;

  float acc[4][4] = {};
  const float* Ap = A + (size_t)(bm + lm) * K + lk;
  const float* Wp = W + (size_t)(bn + lm) * K + lk;

  for (int k0 = 0; k0 < K; k0 += BK) {
    float4 av = *reinterpret_cast<const float4*>(Ap + k0);
    float4 wv = *reinterpret_cast<const float4*>(Wp + k0);
    As[lk + 0][lm] = av.x; As[lk + 1][lm] = av.y;
    As[lk + 2][lm] = av.z; As[lk + 3][lm] = av.w;
    Ws[lk + 0][lm] = wv.x; Ws[lk + 1][lm] = wv.y;
    Ws[lk + 2][lm] = wv.z; Ws[lk + 3][lm] = wv.w;
    __syncthreads();
#pragma unroll
    for (int kk = 0; kk < BK; ++kk) {
      float4 a4 = *reinterpret_cast<const float4*>(&As[kk][ty << 2]);
      float4 w4 = *reinterpret_cast<const float4*>(&Ws[kk][tx << 2]);
      float a[4] = {a4.x, a4.y, a4.z, a4.w};
      float w[4] = {w4.x, w4.y, w4.z, w4.w};
#pragma unroll
      for (int i = 0; i < 4; ++i)
#pragma unroll
        for (int jj = 0; jj < 4; ++jj)
          acc[i][jj] = fmaf(a[i], w[jj], acc[i][jj]);
    }
    __syncthreads();
  }

  const int n0 = bn + (tx << 2);
  float b4[4];
#pragma unroll
  for (int jj = 0; jj < 4; ++jj) b4[jj] = bias[n0 + jj];
  float scale = 1.f;
  if (EPI == 1) {
    int chn = n0 / 768;
    float ls = log_s[chn];
    ls = fminf(fmaxf(ls, -10.f), 10.f);
    scale = __expf(-ls);
  }
#pragma unroll
  for (int i = 0; i < 4; ++i) {
    const int m = bm + (ty << 2) + i;
    float vals[4];
    float4 r4;
    if (EPI == 2) r4 = *reinterpret_cast<const float4*>(R + (size_t)m * N + n0);
#pragma unroll
    for (int jj = 0; jj < 4; ++jj) {
      float v = acc[i][jj];
      if (EPI == 1) v *= scale;
      v += b4[jj];
      if (EPI == 2) v += (jj == 0 ? r4.x : jj == 1 ? r4.y : jj == 2 ? r4.z : r4.w);
      if (RELU) v = fmaxf(v, 0.f);
      vals[jj] = v;
    }
    float4 o; o.x = vals[0]; o.y = vals[1]; o.z = vals[2]; o.w = vals[3];
    *reinterpret_cast<float4*>(C + (size_t)m * N + n0) = o;
  }
}

// ---------------------------------------------------------------------------
// LayerNorm over 1024 features (unchanged).
// ---------------------------------------------------------------------------
template<bool ADD>
__global__ __launch_bounds__(256) void ln_kernel(const float* __restrict__ X,
                                                 const float* __restrict__ Yad,
                                                 float* __restrict__ O)
{
  const int row = blockIdx.x, t = threadIdx.x;
  float4 v = reinterpret_cast<const float4*>(X + (size_t)row * NST)[t];
  if (ADD) {
    float4 w = reinterpret_cast<const float4*>(Yad + (size_t)row * NST)[t];
    v.x += w.x; v.y += w.y; v.z += w.z; v.w += w.w;
  }
  float s  = v.x + v.y + v.z + v.w;
  float ss = v.x * v.x + v.y * v.y + v.z * v.z + v.w * v.w;
#pragma unroll
  for (int m = 1; m < 64; m <<= 1) {
    s  += __shfl_xor(s, m, 64);
    ss += __shfl_xor(ss, m, 64);
  }
  __shared__ float ps[4], pss[4];
  const int wv = t >> 6;
  if ((t & 63) == 0) { ps[wv] = s; pss[wv] = ss; }
  __syncthreads();
  s  = ps[0] + ps[1] + ps[2] + ps[3];
  ss = pss[0] + pss[1] + pss[2] + pss[3];
  const float mean = s * (1.f / 1024.f);
  const float var  = ss * (1.f / 1024.f) - mean * mean;
  const float rstd = rsqrtf(var + 1e-5f);
  v.x = (v.x - mean) * rstd; v.y = (v.y - mean) * rstd;
  v.z = (v.z - mean) * rstd; v.w = (v.w - mean) * rstd;
  reinterpret_cast<float4*>(O + (size_t)row * NST)[t] = v;
}

// ---------------------------------------------------------------------------
// ScaleGRU scan v3: grid=4 (1 block/channel), 1024 threads (16 waves,
// 4/SIMD -> the compiler's default 128-VGPR budget is now the CORRECT
// budget). Thread (u=j>>2, c=j&3) owns gate-rows {u,u+256,u+512} over cols
// [64c,64c+64) = 96 f16x2 weight regs, loaded from the prep cache with NO
// conversion. Live set ~125 regs. h f16 in LDS (double-buffered, 144B chunk
// stride: banks 4(c+q) mod 32 disjoint; 16-lane same-address broadcast).
// Quad DPP butterfly reduces the 4 column-chunks; gates 4x redundant; one
// lgkm-only barrier per step (vmcnt NOT drained: ig prefetch + y stores
// stay in flight).
// ---------------------------------------------------------------------------
#define SCAN_BAR() asm volatile("s_waitcnt lgkmcnt(0)\n\ts_barrier" ::: "memory")

#define DW(k) f16x2 W##k;
#define DECL96 \
  DW(0) DW(1) DW(2) DW(3) DW(4) DW(5) DW(6) DW(7) DW(8) DW(9) DW(10) DW(11) \
  DW(12) DW(13) DW(14) DW(15) DW(16) DW(17) DW(18) DW(19) DW(20) DW(21) DW(22) DW(23) \
  DW(24) DW(25) DW(26) DW(27) DW(28) DW(29) DW(30) DW(31) DW(32) DW(33) DW(34) DW(35) \
  DW(36) DW(37) DW(38) DW(39) DW(40) DW(41) DW(42) DW(43) DW(44) DW(45) DW(46) DW(47) \
  DW(48) DW(49) DW(50) DW(51) DW(52) DW(53) DW(54) DW(55) DW(56) DW(57) DW(58) DW(59) \
  DW(60) DW(61) DW(62) DW(63) DW(64) DW(65) DW(66) DW(67) DW(68) DW(69) DW(70) DW(71) \
  DW(72) DW(73) DW(74) DW(75) DW(76) DW(77) DW(78) DW(79) DW(80) DW(81) DW(82) DW(83) \
  DW(84) DW(85) DW(86) DW(87) DW(88) DW(89) DW(90) DW(91) DW(92) DW(93) DW(94) DW(95)

#define LQ(q, a, b, cc, d) { \
  float4 v = wp4[(q) * 1024]; \
  W##a  = __builtin_bit_cast(f16x2, v.x); \
  W##b  = __builtin_bit_cast(f16x2, v.y); \
  W##cc = __builtin_bit_cast(f16x2, v.z); \
  W##d  = __builtin_bit_cast(f16x2, v.w); }

#define LOAD96 \
  LQ(0,0,1,2,3)     LQ(1,4,5,6,7)     LQ(2,8,9,10,11)   LQ(3,12,13,14,15) \
  LQ(4,16,17,18,19) LQ(5,20,21,22,23) LQ(6,24,25,26,27) LQ(7,28,29,30,31) \
  LQ(8,32,33,34,35) LQ(9,36,37,38,39) LQ(10,40,41,42,43) LQ(11,44,45,46,47) \
  LQ(12,48,49,50,51) LQ(13,52,53,54,55) LQ(14,56,57,58,59) LQ(15,60,61,62,63) \
  LQ(16,64,65,66,67) LQ(17,68,69,70,71) LQ(18,72,73,74,75) LQ(19,76,77,78,79) \
  LQ(20,80,81,82,83) LQ(21,84,85,86,87) LQ(22,88,89,90,91) LQ(23,92,93,94,95)

// one float4 of h (4 pairs) x 3 gate rows = 12 dot2; same-acc spacing 3 instr
#define DQ(cq, r0,r1,r2,r3, z0,z1,z2,z3, n0,n1,n2,n3) { \
  float4 hv = hl4[cq]; \
  f16x2 hp0 = __builtin_bit_cast(f16x2, hv.x); \
  f16x2 hp1 = __builtin_bit_cast(f16x2, hv.y); \
  f16x2 hp2 = __builtin_bit_cast(f16x2, hv.z); \
  f16x2 hp3 = __builtin_bit_cast(f16x2, hv.w); \
  ar = fdot2f(W##r0, hp0, ar); az = fdot2f(W##z0, hp0, az); an = fdot2f(W##n0, hp0, an); \
  ar = fdot2f(W##r1, hp1, ar); az = fdot2f(W##z1, hp1, az); an = fdot2f(W##n1, hp1, an); \
  ar = fdot2f(W##r2, hp2, ar); az = fdot2f(W##z2, hp2, az); an = fdot2f(W##n2, hp2, an); \
  ar = fdot2f(W##r3, hp3, ar); az = fdot2f(W##z3, hp3, az); an = fdot2f(W##n3, hp3, an); }

#define DOT96 \
  DQ(0, 0,1,2,3,     32,33,34,35, 64,65,66,67) \
  DQ(1, 4,5,6,7,     36,37,38,39, 68,69,70,71) \
  DQ(2, 8,9,10,11,   40,41,42,43, 72,73,74,75) \
  DQ(3, 12,13,14,15, 44,45,46,47, 76,77,78,79) \
  DQ(4, 16,17,18,19, 48,49,50,51, 80,81,82,83) \
  DQ(5, 20,21,22,23, 52,53,54,55, 84,85,86,87) \
  DQ(6, 24,25,26,27, 56,57,58,59, 88,89,90,91) \
  DQ(7, 28,29,30,31, 60,61,62,63, 92,93,94,95)

__global__ __launch_bounds__(1024) void scan_kernel(
    const float4* __restrict__ wswL,  // layer's f16 weight cache [4][24][1024]x16B
    const float* __restrict__ bn_,    // [NCH,256]
    const float* __restrict__ log_s,  // [NCH]
    const float* __restrict__ ig,     // [T, 3072]
    const float* __restrict__ h0,     // [256]
    float* __restrict__ y)            // [T, 1024]
{
  const int ch = blockIdx.x;
  const int j  = threadIdx.x;
  const int u  = j >> 2, c = j & 3;
  const float* igc = ig + ch * 768;
  float* yc        = y + ch * GHH;

  DECL96
  const float4* wp4 = wswL + (size_t)ch * 24 * 1024 + j;
  LOAD96

  const float bnj = bn_[ch * GHH + u];
  float ls = log_s[ch];
  ls = fminf(fmaxf(ls, -10.f), 10.f);
  const float inv_s = __expf(-ls);
  float h = h0[u];

  // h: 2 buffers x 4 chunks x 144B (128B data + 16B pad)
  __shared__ __align__(16) unsigned char hsh[2][576];
  const int wb = ((u >> 6) * 144) + ((u & 63) * 2);
  if (c == 0)
    *reinterpret_cast<_Float16*>(&hsh[0][wb]) = (_Float16)h;
  SCAN_BAR();

  // depth-1 ig prefetch (ig was just written by the GEMM -> L3-resident)
  float ir = igc[u], iz = igc[256 + u], in_ = igc[512 + u];

  for (int t = 0; t < T_SEQ; ++t) {
    float nr = 0.f, nz = 0.f, nn = 0.f;
    if (t + 1 < T_SEQ) {
      const float* p = igc + (size_t)(t + 1) * LD_IG;
      nr = p[u]; nz = p[256 + u]; nn = p[512 + u];
    }
    float ar = 0.f, az = 0.f, an = 0.f;
    const float4* hl4 = reinterpret_cast<const float4*>(&hsh[t & 1][c * 144]);
    DOT96
    // reduce the 4 column-chunks within each quad (VALU pipe)
    ar = dpp_xor_add<0xB1>(ar); az = dpp_xor_add<0xB1>(az); an = dpp_xor_add<0xB1>(an);
    ar = dpp_xor_add<0x4E>(ar); az = dpp_xor_add<0x4E>(az); an = dpp_xor_add<0x4E>(an);
    // gates (redundant across the quad; identical inputs -> identical h)
    const float rg = sigmoid_f(ir + ar);
    const float zg = sigmoid_f(iz + az);
    const float ng = tanh_f(in_ + rg * (an + bnj));
    const float hnew = ng + zg * (h - ng);
    h = (hnew - h) * inv_s + h;
    if (c == 0) {
      yc[(size_t)t * NST + u] = h;
      *reinterpret_cast<_Float16*>(&hsh[(t + 1) & 1][wb]) = (_Float16)h;
    }
    SCAN_BAR();
    ir = nr; iz = nz; in_ = nn;
  }
}

// ---------------------------------------------------------------------------
// Classifier second GEMM: N=10, K=1024. One block per row (unchanged).
// ---------------------------------------------------------------------------
__global__ __launch_bounds__(256) void gemv_cls(const float* __restrict__ A,
                                                const float* __restrict__ W,
                                                const float* __restrict__ b,
                                                float* __restrict__ out)
{
  const int m = blockIdx.x, t = threadIdx.x;
  float4 a = reinterpret_cast<const float4*>(A + (size_t)m * NST)[t];
  float p[10];
#pragma unroll
  for (int n = 0; n < 10; ++n) {
    float4 w = reinterpret_cast<const float4*>(W + (size_t)n * NST)[t];
    p[n] = a.x * w.x + a.y * w.y + a.z * w.z + a.w * w.w;
  }
#pragma unroll
  for (int n = 0; n < 10; ++n)
#pragma unroll
    for (int msk = 1; msk < 64; msk <<= 1) p[n] += __shfl_xor(p[n], msk, 64);
  __shared__ float red[4][10];
  const int wv = t >> 6;
  if ((t & 63) == 0) {
#pragma unroll
    for (int n = 0; n < 10; ++n) red[wv][n] = p[n];
  }
  __syncthreads();
  if (t < 10) {
    float v = red[0][t] + red[1][t] + red[2][t] + red[3][t] + b[t];
    out[(size_t)m * 10 + t] = v;
  }
}

// ---------------------------------------------------------------------------
extern "C" void kernel_launch(void* const* d_in, const int* in_sizes, int n_in,
                              void* d_out, int out_size, void* d_ws, size_t ws_size,
                              hipStream_t stream) {
  const float* inputs = (const float*)d_in[0];
  const float* h0     = (const float*)d_in[1];
  // d_in[2] = yinit_guess: unused (exact solution independent of it)
  const float* enc_w1 = (const float*)d_in[3];
  const float* enc_b1 = (const float*)d_in[4];
  const float* enc_w2 = (const float*)d_in[5];
  const float* enc_b2 = (const float*)d_in[6];
  const float* gwih   = (const float*)d_in[7];   // [3,4,768,1024]
  const float* gwhh   = (const float*)d_in[8];   // [3,4,768,256]
  const float* gb     = (const float*)d_in[9];   // [3,4,768]
  const float* gbn    = (const float*)d_in[10];  // [3,4,256]
  const float* gls    = (const float*)d_in[11];  // [3,4,1]
  const float* mw1    = (const float*)d_in[12];
  const float* mb1    = (const float*)d_in[13];
  const float* mw2    = (const float*)d_in[14];
  const float* mb2    = (const float*)d_in[15];
  const float* cw1    = (const float*)d_in[16];
  const float* cb1    = (const float*)d_in[17];
  const float* cw2    = (const float*)d_in[18];
  const float* cb2    = (const float*)d_in[19];
  float* out = (float*)d_out;

  char* ws = (char*)d_ws;
  float* bufA = (float*)ws;                          // [8192,1024] 33.5MB
  float* bufB = (float*)(ws + (size_t)33554432);     // [8192,1024] 33.5MB
  float* bufG = (float*)(ws + (size_t)67108864);     // [8192,3072] 100.7MB (ig / mlp hidden)
  float4* gw16 = (float4*)(ws + (size_t)GW_OFF);     // f16 whh cache, 4.7MB

  const dim3 blk(256);
  const dim3 gemm_1024(8192 / 64, 1024 / 64);
  const dim3 gemm_3072(8192 / 64, 3072 / 64);

  // weight cache (independent of encoder; stream-ordered before first scan)
  prep_whh<<<dim3(1152), blk, 0, stream>>>(gwhh, (f16x2*)gw16);

  // encoder
  gemm_f32<0, true ><<<gemm_1024, blk, 0, stream>>>(inputs, enc_w1, enc_b1, nullptr,
                                                    bufG, 8192, 1024, 128, nullptr);
  gemm_f32<0, false><<<gemm_1024, blk, 0, stream>>>(bufG, enc_w2, enc_b2, nullptr,
                                                    bufA, 8192, 1024, 1024, nullptr);
  float* x  = bufA;
  float* xb = bufB;
  for (int i = 0; i < 3; ++i) {
    ln_kernel<false><<<dim3(8192), blk, 0, stream>>>(x, nullptr, xb);
    gemm_f32<1, false><<<gemm_3072, blk, 0, stream>>>(xb, gwih + (size_t)i * 4 * 768 * 1024,
                                                      gb + (size_t)i * 3072, nullptr,
                                                      bufG, 8192, 3072, 1024,
                                                      gls + (size_t)i * 4);
    scan_kernel<<<dim3(4), dim3(1024), 0, stream>>>(gw16 + (size_t)i * 98304,
                                                    gbn + (size_t)i * 1024,
                                                    gls + (size_t)i * 4,
                                                    bufG, h0, x);
    ln_kernel<true><<<dim3(8192), blk, 0, stream>>>(x, xb, x);
    gemm_f32<0, true ><<<gemm_1024, blk, 0, stream>>>(x, mw1 + (size_t)i * 1048576,
                                                      mb1 + (size_t)i * 1024, nullptr,
                                                      bufG, 8192, 1024, 1024, nullptr);
    gemm_f32<2, false><<<gemm_1024, blk, 0, stream>>>(bufG, mw2 + (size_t)i * 1048576,
                                                      mb2 + (size_t)i * 1024, x,
                                                      xb, 8192, 1024, 1024, nullptr);
    float* tmp = x; x = xb; xb = tmp;
  }
  // classifier
  gemm_f32<0, true><<<gemm_1024, blk, 0, stream>>>(x, cw1, cb1, nullptr,
                                                   bufG, 8192, 1024, 1024, nullptr);
  gemv_cls<<<dim3(8192), blk, 0, stream>>>(bufG, cw2, cb2, out);
}

// Round 6
// 36851.376 us; speedup vs baseline: 1.0400x; 1.0069x over previous
//
#include <hip/hip_runtime.h>

// MultiScaleGRU: T=8192, NINP=128, NSTATE=1024, NCH=4, GH=256, NLAYER=3, NCLASS=10
#define T_SEQ 8192
#define NST   1024
#define GHH   256
#define LD_IG 3072        // 4 channels * 768 ig columns
#define GW_OFF 167772160  // byte offset of f16 weight cache in ws (after bufG)

typedef _Float16 f16x2 __attribute__((ext_vector_type(2)));

#if defined(__has_builtin)
#if __has_builtin(__builtin_amdgcn_fdot2)
#define HAVE_FDOT2 1
#endif
#endif

__device__ __forceinline__ float fdot2f(f16x2 a, f16x2 b, float c) {
#ifdef HAVE_FDOT2
  return __builtin_amdgcn_fdot2(a, b, c, false);
#else
  float d;
  asm("v_dot2_f32_f16 %0, %1, %2, %3" : "=v"(d) : "v"(a), "v"(b), "v"(c));
  return d;
#endif
}

// quad-lane XOR butterfly add via DPP (VALU pipe)
template<int CTRL>
__device__ __forceinline__ float dpp_xor_add(float x) {
#if defined(__has_builtin) && __has_builtin(__builtin_amdgcn_update_dpp)
  int s = __builtin_amdgcn_update_dpp(0, __builtin_bit_cast(int, x), CTRL, 0xF, 0xF, true);
  return x + __builtin_bit_cast(float, s);
#else
  return x + __shfl_xor(x, (CTRL == 0xB1) ? 1 : 2, 64);
#endif
}

__device__ __forceinline__ float sigmoid_f(float x) {
  return 1.0f / (1.0f + __expf(-x));
}
__device__ __forceinline__ float tanh_f(float x) {
  float ax = fabsf(x);
  float e = __expf(-2.0f * ax);
  float t = (1.0f - e) / (1.0f + e);
  return copysignf(t, x);
}

// ---------------------------------------------------------------------------
// Prep: convert whh [3,4,768,256] f32 -> f16x2 cache (unchanged from R5).
// Layout: [lc=l*4+ch][q 0..23][jj 0..1023] x 16B; element (q,jj,e) = weight
// flat f=4q+e of thread jj: row r=f>>5 (r/z/n), pair k=f&31, unit u=jj>>2,
// chunk c=jj&3 -> whh[lc][r*256+u][c*64 + 2k, 2k+1].
// ---------------------------------------------------------------------------
__global__ __launch_bounds__(256) void prep_whh(const float* __restrict__ whh,
                                                f16x2* __restrict__ wsw)
{
  const int idx = blockIdx.x * 256 + threadIdx.x;   // 0 .. 294911
  const int jj = idx & 1023;
  const int q  = (idx >> 10) % 24;
  const int lc = idx / (24 * 1024);
  const int u = jj >> 2, c = jj & 3;
  const int r = q >> 3, kb = (q & 7) * 4;           // pairs kb..kb+3
  const float* src = whh + (((size_t)lc * 768 + r * 256 + u) * 256) + c * 64 + 2 * kb;
  float4 a = *reinterpret_cast<const float4*>(src);
  float4 b = *reinterpret_cast<const float4*>(src + 4);
  f16x2* dst = wsw + (size_t)idx * 4;
  dst[0] = f16x2{(_Float16)a.x, (_Float16)a.y};
  dst[1] = f16x2{(_Float16)a.z, (_Float16)a.w};
  dst[2] = f16x2{(_Float16)b.x, (_Float16)b.y};
  dst[3] = f16x2{(_Float16)b.z, (_Float16)b.w};
}

// ---------------------------------------------------------------------------
// f32 tiled GEMM (unchanged): C[M,N] = epi(A[M,K] @ W[N,K]^T).
// ---------------------------------------------------------------------------
template<int EPI, bool RELU>
__global__ __launch_bounds__(256) void gemm_f32(
    const float* __restrict__ A, const float* __restrict__ W,
    const float* __restrict__ bias, const float* __restrict__ R,
    float* __restrict__ C, int M, int N, int K,
    const float* __restrict__ log_s)
{
  const int BM = 64, BN = 64, BK = 16;
  __shared__ float As[BK][BM + 4];
  __shared__ float Ws[BK][BN + 4];
  const int bm = blockIdx.x * BM, bn = blockIdx.y * BN;
  const int t = threadIdx.x;
  const int tx = t & 15, ty = t >> 4;
  const int lm = t >> 2, lk = (t & 3) << 2;

  float acc[4][4] = {};
  const float* Ap = A + (size_t)(bm + lm) * K + lk;
  const float* Wp = W + (size_t)(bn + lm) * K + lk;

  for (int k0 = 0; k0 < K; k0 += BK) {
    float4 av = *reinterpret_cast<const float4*>(Ap + k0);
    float4 wv = *reinterpret_cast<const float4*>(Wp + k0);
    As[lk + 0][lm] = av.x; As[lk + 1][lm] = av.y;
    As[lk + 2][lm] = av.z; As[lk + 3][lm] = av.w;
    Ws[lk + 0][lm] = wv.x; Ws[lk + 1][lm] = wv.y;
    Ws[lk + 2][lm] = wv.z; Ws[lk + 3][lm] = wv.w;
    __syncthreads();
#pragma unroll
    for (int kk = 0; kk < BK; ++kk) {
      float4 a4 = *reinterpret_cast<const float4*>(&As[kk][ty << 2]);
      float4 w4 = *reinterpret_cast<const float4*>(&Ws[kk][tx << 2]);
      float a[4] = {a4.x, a4.y, a4.z, a4.w};
      float w[4] = {w4.x, w4.y, w4.z, w4.w};
#pragma unroll
      for (int i = 0; i < 4; ++i)
#pragma unroll
        for (int jj = 0; jj < 4; ++jj)
          acc[i][jj] = fmaf(a[i], w[jj], acc[i][jj]);
    }
    __syncthreads();
  }

  const int n0 = bn + (tx << 2);
  float b4[4];
#pragma unroll
  for (int jj = 0; jj < 4; ++jj) b4[jj] = bias[n0 + jj];
  float scale = 1.f;
  if (EPI == 1) {
    int chn = n0 / 768;
    float ls = log_s[chn];
    ls = fminf(fmaxf(ls, -10.f), 10.f);
    scale = __expf(-ls);
  }
#pragma unroll
  for (int i = 0; i < 4; ++i) {
    const int m = bm + (ty << 2) + i;
    float vals[4];
    float4 r4;
    if (EPI == 2) r4 = *reinterpret_cast<const float4*>(R + (size_t)m * N + n0);
#pragma unroll
    for (int jj = 0; jj < 4; ++jj) {
      float v = acc[i][jj];
      if (EPI == 1) v *= scale;
      v += b4[jj];
      if (EPI == 2) v += (jj == 0 ? r4.x : jj == 1 ? r4.y : jj == 2 ? r4.z : r4.w);
      if (RELU) v = fmaxf(v, 0.f);
      vals[jj] = v;
    }
    float4 o; o.x = vals[0]; o.y = vals[1]; o.z = vals[2]; o.w = vals[3];
    *reinterpret_cast<float4*>(C + (size_t)m * N + n0) = o;
  }
}

// ---------------------------------------------------------------------------
// LayerNorm over 1024 features (unchanged).
// ---------------------------------------------------------------------------
template<bool ADD>
__global__ __launch_bounds__(256) void ln_kernel(const float* __restrict__ X,
                                                 const float* __restrict__ Yad,
                                                 float* __restrict__ O)
{
  const int row = blockIdx.x, t = threadIdx.x;
  float4 v = reinterpret_cast<const float4*>(X + (size_t)row * NST)[t];
  if (ADD) {
    float4 w = reinterpret_cast<const float4*>(Yad + (size_t)row * NST)[t];
    v.x += w.x; v.y += w.y; v.z += w.z; v.w += w.w;
  }
  float s  = v.x + v.y + v.z + v.w;
  float ss = v.x * v.x + v.y * v.y + v.z * v.z + v.w * v.w;
#pragma unroll
  for (int m = 1; m < 64; m <<= 1) {
    s  += __shfl_xor(s, m, 64);
    ss += __shfl_xor(ss, m, 64);
  }
  __shared__ float ps[4], pss[4];
  const int wv = t >> 6;
  if ((t & 63) == 0) { ps[wv] = s; pss[wv] = ss; }
  __syncthreads();
  s  = ps[0] + ps[1] + ps[2] + ps[3];
  ss = pss[0] + pss[1] + pss[2] + pss[3];
  const float mean = s * (1.f / 1024.f);
  const float var  = ss * (1.f / 1024.f) - mean * mean;
  const float rstd = rsqrtf(var + 1e-5f);
  v.x = (v.x - mean) * rstd; v.y = (v.y - mean) * rstd;
  v.z = (v.z - mean) * rstd; v.w = (v.w - mean) * rstd;
  reinterpret_cast<float4*>(O + (size_t)row * NST)[t] = v;
}

// ---------------------------------------------------------------------------
// ScaleGRU scan v4. Same R5 layout (1024 thr, u=j>>2, c=j&3, 96 f16x2/thread
// from the no-convert prep cache). Two fixes vs R5:
//  (1) amdgpu_waves_per_eu(4,4): the allocator budgets VGPRs for its default
//      occupancy target (512thr->4/EU->128 regs in R2/R3, 1024thr->8/EU->64
//      in R5). Pin 4/EU so the budget is 128 — a value it provably grants.
//  (2) keep transient pressure under that budget: the 8 h ds_read_b128 were
//      free to cluster (+32 regs -> peak ~155 -> whole weight class spilled).
//      Depth-2 pipeline over named hvA/hvB with sched_barrier(0) fences
//      caps peak at ~124.
// ---------------------------------------------------------------------------
#define SCAN_BAR() asm volatile("s_waitcnt lgkmcnt(0)\n\ts_barrier" ::: "memory")
#define SB0() __builtin_amdgcn_sched_barrier(0)

#define DW(k) f16x2 W##k;
#define DECL96 \
  DW(0) DW(1) DW(2) DW(3) DW(4) DW(5) DW(6) DW(7) DW(8) DW(9) DW(10) DW(11) \
  DW(12) DW(13) DW(14) DW(15) DW(16) DW(17) DW(18) DW(19) DW(20) DW(21) DW(22) DW(23) \
  DW(24) DW(25) DW(26) DW(27) DW(28) DW(29) DW(30) DW(31) DW(32) DW(33) DW(34) DW(35) \
  DW(36) DW(37) DW(38) DW(39) DW(40) DW(41) DW(42) DW(43) DW(44) DW(45) DW(46) DW(47) \
  DW(48) DW(49) DW(50) DW(51) DW(52) DW(53) DW(54) DW(55) DW(56) DW(57) DW(58) DW(59) \
  DW(60) DW(61) DW(62) DW(63) DW(64) DW(65) DW(66) DW(67) DW(68) DW(69) DW(70) DW(71) \
  DW(72) DW(73) DW(74) DW(75) DW(76) DW(77) DW(78) DW(79) DW(80) DW(81) DW(82) DW(83) \
  DW(84) DW(85) DW(86) DW(87) DW(88) DW(89) DW(90) DW(91) DW(92) DW(93) DW(94) DW(95)

#define LQ(q, a, b, cc, d) { \
  float4 v = wp4[(q) * 1024]; \
  W##a  = __builtin_bit_cast(f16x2, v.x); \
  W##b  = __builtin_bit_cast(f16x2, v.y); \
  W##cc = __builtin_bit_cast(f16x2, v.z); \
  W##d  = __builtin_bit_cast(f16x2, v.w); }

#define LOAD96 \
  LQ(0,0,1,2,3)     LQ(1,4,5,6,7)     LQ(2,8,9,10,11)   LQ(3,12,13,14,15) \
  LQ(4,16,17,18,19) LQ(5,20,21,22,23) LQ(6,24,25,26,27) LQ(7,28,29,30,31) \
  LQ(8,32,33,34,35) LQ(9,36,37,38,39) LQ(10,40,41,42,43) LQ(11,44,45,46,47) \
  LQ(12,48,49,50,51) LQ(13,52,53,54,55) LQ(14,56,57,58,59) LQ(15,60,61,62,63) \
  LQ(16,64,65,66,67) LQ(17,68,69,70,71) LQ(18,72,73,74,75) LQ(19,76,77,78,79) \
  LQ(20,80,81,82,83) LQ(21,84,85,86,87) LQ(22,88,89,90,91) LQ(23,92,93,94,95)

// 12 dot2 against one float4 of h (4 pairs x 3 gate rows)
#define DOTS(hv, r0,r1,r2,r3, z0,z1,z2,z3, n0,n1,n2,n3) { \
  f16x2 hp0 = __builtin_bit_cast(f16x2, hv.x); \
  f16x2 hp1 = __builtin_bit_cast(f16x2, hv.y); \
  f16x2 hp2 = __builtin_bit_cast(f16x2, hv.z); \
  f16x2 hp3 = __builtin_bit_cast(f16x2, hv.w); \
  ar = fdot2f(W##r0, hp0, ar); az = fdot2f(W##z0, hp0, az); an = fdot2f(W##n0, hp0, an); \
  ar = fdot2f(W##r1, hp1, ar); az = fdot2f(W##z1, hp1, az); an = fdot2f(W##n1, hp1, an); \
  ar = fdot2f(W##r2, hp2, ar); az = fdot2f(W##z2, hp2, az); an = fdot2f(W##n2, hp2, an); \
  ar = fdot2f(W##r3, hp3, ar); az = fdot2f(W##z3, hp3, az); an = fdot2f(W##n3, hp3, an); }

__global__ __attribute__((amdgpu_flat_work_group_size(1024, 1024),
                          amdgpu_waves_per_eu(4, 4)))
void scan_kernel(
    const float4* __restrict__ wswL,  // layer's f16 weight cache [4][24][1024]x16B
    const float* __restrict__ bn_,    // [NCH,256]
    const float* __restrict__ log_s,  // [NCH]
    const float* __restrict__ ig,     // [T, 3072]
    const float* __restrict__ h0,     // [256]
    float* __restrict__ y)            // [T, 1024]
{
  const int ch = blockIdx.x;
  const int j  = threadIdx.x;
  const int u  = j >> 2, c = j & 3;
  const float* igc = ig + ch * 768;
  float* yc        = y + ch * GHH;

  DECL96
  const float4* wp4 = wswL + (size_t)ch * 24 * 1024 + j;
  LOAD96

  const float bnj = bn_[ch * GHH + u];
  float ls = log_s[ch];
  ls = fminf(fmaxf(ls, -10.f), 10.f);
  const float inv_s = __expf(-ls);
  float h = h0[u];

  // h: 2 buffers x 4 chunks x 144B (128B data + 16B pad -> banks 4(c+k) disjoint)
  __shared__ __align__(16) unsigned char hsh[2][576];
  const int wb = ((u >> 6) * 144) + ((u & 63) * 2);
  if (c == 0)
    *reinterpret_cast<_Float16*>(&hsh[0][wb]) = (_Float16)h;
  SCAN_BAR();

  // depth-1 ig prefetch (ig just written by the GEMM -> L2/L3-resident)
  float ir = igc[u], iz = igc[256 + u], in_ = igc[512 + u];

  for (int t = 0; t < T_SEQ; ++t) {
    float nr = 0.f, nz = 0.f, nn = 0.f;
    if (t + 1 < T_SEQ) {
      const float* p = igc + (size_t)(t + 1) * LD_IG;
      nr = p[u]; nz = p[256 + u]; nn = p[512 + u];
    }
    float ar = 0.f, az = 0.f, an = 0.f;
    const float4* hl4 = reinterpret_cast<const float4*>(&hsh[t & 1][c * 144]);
    // depth-2 pipelined h loads: only hvA/hvB (8 regs) in flight, never 32
    float4 hvA = hl4[0];
    float4 hvB = hl4[1];
    DOTS(hvA, 0,1,2,3,     32,33,34,35, 64,65,66,67)
    SB0();
    hvA = hl4[2];
    DOTS(hvB, 4,5,6,7,     36,37,38,39, 68,69,70,71)
    SB0();
    hvB = hl4[3];
    DOTS(hvA, 8,9,10,11,   40,41,42,43, 72,73,74,75)
    SB0();
    hvA = hl4[4];
    DOTS(hvB, 12,13,14,15, 44,45,46,47, 76,77,78,79)
    SB0();
    hvB = hl4[5];
    DOTS(hvA, 16,17,18,19, 48,49,50,51, 80,81,82,83)
    SB0();
    hvA = hl4[6];
    DOTS(hvB, 20,21,22,23, 52,53,54,55, 84,85,86,87)
    SB0();
    hvB = hl4[7];
    DOTS(hvA, 24,25,26,27, 56,57,58,59, 88,89,90,91)
    SB0();
    DOTS(hvB, 28,29,30,31, 60,61,62,63, 92,93,94,95)
    // reduce the 4 column-chunks within each quad (VALU pipe)
    ar = dpp_xor_add<0xB1>(ar); az = dpp_xor_add<0xB1>(az); an = dpp_xor_add<0xB1>(an);
    ar = dpp_xor_add<0x4E>(ar); az = dpp_xor_add<0x4E>(az); an = dpp_xor_add<0x4E>(an);
    // gates (redundant across the quad; identical inputs -> identical h)
    const float rg = sigmoid_f(ir + ar);
    const float zg = sigmoid_f(iz + az);
    const float ng = tanh_f(in_ + rg * (an + bnj));
    const float hnew = ng + zg * (h - ng);
    h = (hnew - h) * inv_s + h;
    if (c == 0) {
      yc[(size_t)t * NST + u] = h;
      *reinterpret_cast<_Float16*>(&hsh[(t + 1) & 1][wb]) = (_Float16)h;
    }
    SCAN_BAR();
    ir = nr; iz = nz; in_ = nn;
  }
}

// ---------------------------------------------------------------------------
// Classifier second GEMM: N=10, K=1024. One block per row (unchanged).
// ---------------------------------------------------------------------------
__global__ __launch_bounds__(256) void gemv_cls(const float* __restrict__ A,
                                                const float* __restrict__ W,
                                                const float* __restrict__ b,
                                                float* __restrict__ out)
{
  const int m = blockIdx.x, t = threadIdx.x;
  float4 a = reinterpret_cast<const float4*>(A + (size_t)m * NST)[t];
  float p[10];
#pragma unroll
  for (int n = 0; n < 10; ++n) {
    float4 w = reinterpret_cast<const float4*>(W + (size_t)n * NST)[t];
    p[n] = a.x * w.x + a.y * w.y + a.z * w.z + a.w * w.w;
  }
#pragma unroll
  for (int n = 0; n < 10; ++n)
#pragma unroll
    for (int msk = 1; msk < 64; msk <<= 1) p[n] += __shfl_xor(p[n], msk, 64);
  __shared__ float red[4][10];
  const int wv = t >> 6;
  if ((t & 63) == 0) {
#pragma unroll
    for (int n = 0; n < 10; ++n) red[wv][n] = p[n];
  }
  __syncthreads();
  if (t < 10) {
    float v = red[0][t] + red[1][t] + red[2][t] + red[3][t] + b[t];
    out[(size_t)m * 10 + t] = v;
  }
}

// ---------------------------------------------------------------------------
extern "C" void kernel_launch(void* const* d_in, const int* in_sizes, int n_in,
                              void* d_out, int out_size, void* d_ws, size_t ws_size,
                              hipStream_t stream) {
  const float* inputs = (const float*)d_in[0];
  const float* h0     = (const float*)d_in[1];
  // d_in[2] = yinit_guess: unused (exact solution independent of it)
  const float* enc_w1 = (const float*)d_in[3];
  const float* enc_b1 = (const float*)d_in[4];
  const float* enc_w2 = (const float*)d_in[5];
  const float* enc_b2 = (const float*)d_in[6];
  const float* gwih   = (const float*)d_in[7];   // [3,4,768,1024]
  const float* gwhh   = (const float*)d_in[8];   // [3,4,768,256]
  const float* gb     = (const float*)d_in[9];   // [3,4,768]
  const float* gbn    = (const float*)d_in[10];  // [3,4,256]
  const float* gls    = (const float*)d_in[11];  // [3,4,1]
  const float* mw1    = (const float*)d_in[12];
  const float* mb1    = (const float*)d_in[13];
  const float* mw2    = (const float*)d_in[14];
  const float* mb2    = (const float*)d_in[15];
  const float* cw1    = (const float*)d_in[16];
  const float* cb1    = (const float*)d_in[17];
  const float* cw2    = (const float*)d_in[18];
  const float* cb2    = (const float*)d_in[19];
  float* out = (float*)d_out;

  char* ws = (char*)d_ws;
  float* bufA = (float*)ws;                          // [8192,1024] 33.5MB
  float* bufB = (float*)(ws + (size_t)33554432);     // [8192,1024] 33.5MB
  float* bufG = (float*)(ws + (size_t)67108864);     // [8192,3072] 100.7MB (ig / mlp hidden)
  float4* gw16 = (float4*)(ws + (size_t)GW_OFF);     // f16 whh cache, 4.7MB

  const dim3 blk(256);
  const dim3 gemm_1024(8192 / 64, 1024 / 64);
  const dim3 gemm_3072(8192 / 64, 3072 / 64);

  // weight cache (independent of encoder; stream-ordered before first scan)
  prep_whh<<<dim3(1152), blk, 0, stream>>>(gwhh, (f16x2*)gw16);

  // encoder
  gemm_f32<0, true ><<<gemm_1024, blk, 0, stream>>>(inputs, enc_w1, enc_b1, nullptr,
                                                    bufG, 8192, 1024, 128, nullptr);
  gemm_f32<0, false><<<gemm_1024, blk, 0, stream>>>(bufG, enc_w2, enc_b2, nullptr,
                                                    bufA, 8192, 1024, 1024, nullptr);
  float* x  = bufA;
  float* xb = bufB;
  for (int i = 0; i < 3; ++i) {
    ln_kernel<false><<<dim3(8192), blk, 0, stream>>>(x, nullptr, xb);
    gemm_f32<1, false><<<gemm_3072, blk, 0, stream>>>(xb, gwih + (size_t)i * 4 * 768 * 1024,
                                                      gb + (size_t)i * 3072, nullptr,
                                                      bufG, 8192, 3072, 1024,
                                                      gls + (size_t)i * 4);
    scan_kernel<<<dim3(4), dim3(1024), 0, stream>>>(gw16 + (size_t)i * 98304,
                                                    gbn + (size_t)i * 1024,
                                                    gls + (size_t)i * 4,
                                                    bufG, h0, x);
    ln_kernel<true><<<dim3(8192), blk, 0, stream>>>(x, xb, x);
    gemm_f32<0, true ><<<gemm_1024, blk, 0, stream>>>(x, mw1 + (size_t)i * 1048576,
                                                      mb1 + (size_t)i * 1024, nullptr,
                                                      bufG, 8192, 1024, 1024, nullptr);
    gemm_f32<2, false><<<gemm_1024, blk, 0, stream>>>(bufG, mw2 + (size_t)i * 1048576,
                                                      mb2 + (size_t)i * 1024, x,
                                                      xb, 8192, 1024, 1024, nullptr);
    float* tmp = x; x = xb; xb = tmp;
  }
  // classifier
  gemm_f32<0, true><<<gemm_1024, blk, 0, stream>>>(x, cw1, cb1, nullptr,
                                                   bufG, 8192, 1024, 1024, nullptr);
  gemv_cls<<<dim3(8192), blk, 0, stream>>>(bufG, cw2, cb2, out);
}

// Round 7
// 31504.666 us; speedup vs baseline: 1.2166x; 1.1697x over previous
//
#include <hip/hip_runtime.h>

// MultiScaleGRU: T=8192, NINP=128, NSTATE=1024, NCH=4, GH=256, NLAYER=3, NCLASS=10
#define T_SEQ 8192
#define NST   1024
#define GHH   256
#define LD_IG 3072        // 4 channels * 768 ig columns
#define GW_OFF 167772160  // byte offset of f16 weight cache in ws (after bufG)

typedef _Float16 half8 __attribute__((ext_vector_type(8)));
typedef float f32x4 __attribute__((ext_vector_type(4)));

#define MFMA16(a, b, c) __builtin_amdgcn_mfma_f32_16x16x32_f16(a, b, c, 0, 0, 0)

__device__ __forceinline__ float sigmoid_f(float x) {
  return 1.0f / (1.0f + __expf(-x));
}
__device__ __forceinline__ float tanh_f(float x) {
  float ax = fabsf(x);
  float e = __expf(-2.0f * ax);
  float t = (1.0f - e) / (1.0f + e);
  return copysignf(t, x);
}

// ---------------------------------------------------------------------------
// Prep: whh [3,4,768,256] f32 -> f16 MFMA B-fragment cache.
// Frag (lc, g_id=nb*8+kc, lane l, elem e): B[k][n] for the 16x16x32 f16 MFMA
// with n = l&15 -> unit ub*16+n (nb = g*16+ub, g = gate r/z/n), k = (l>>4)*8+e
// -> col kc*32+k. Scan thread (wave w, lane l) loads frag (w*6+i)*8+kc at
// [lc][g_id][l] as one coalesced 16B load -> lands directly in AGPR class.
// ---------------------------------------------------------------------------
__global__ __launch_bounds__(256) void prep_whh(const float* __restrict__ whh,
                                                half8* __restrict__ wB)
{
  const int idx = blockIdx.x * 256 + threadIdx.x;   // 0 .. 294911
  const int lc  = idx / 24576;                      // layer*4+ch
  const int rem = idx - lc * 24576;
  const int g_id = rem >> 6, l = rem & 63;
  const int nb = g_id >> 3, kc = g_id & 7;
  const int g = nb >> 4, ub = nb & 15;
  const int n = l & 15, kg = l >> 4;
  const int row = g * 256 + ub * 16 + n;
  const int col = kc * 32 + kg * 8;
  const float* src = whh + (size_t)lc * 196608 + (size_t)row * 256 + col;
  float4 x0 = *reinterpret_cast<const float4*>(src);
  float4 x1 = *reinterpret_cast<const float4*>(src + 4);
  half8 o;
  o[0] = (_Float16)x0.x; o[1] = (_Float16)x0.y;
  o[2] = (_Float16)x0.z; o[3] = (_Float16)x0.w;
  o[4] = (_Float16)x1.x; o[5] = (_Float16)x1.y;
  o[6] = (_Float16)x1.z; o[7] = (_Float16)x1.w;
  wB[idx] = o;
}

// ---------------------------------------------------------------------------
// f32 tiled GEMM (unchanged): C[M,N] = epi(A[M,K] @ W[N,K]^T).
// ---------------------------------------------------------------------------
template<int EPI, bool RELU>
__global__ __launch_bounds__(256) void gemm_f32(
    const float* __restrict__ A, const float* __restrict__ W,
    const float* __restrict__ bias, const float* __restrict__ R,
    float* __restrict__ C, int M, int N, int K,
    const float* __restrict__ log_s)
{
  const int BM = 64, BN = 64, BK = 16;
  __shared__ float As[BK][BM + 4];
  __shared__ float Ws[BK][BN + 4];
  const int bm = blockIdx.x * BM, bn = blockIdx.y * BN;
  const int t = threadIdx.x;
  const int tx = t & 15, ty = t >> 4;
  const int lm = t >> 2, lk = (t & 3) << 2;

  float acc[4][4] = {};
  const float* Ap = A + (size_t)(bm + lm) * K + lk;
  const float* Wp = W + (size_t)(bn + lm) * K + lk;

  for (int k0 = 0; k0 < K; k0 += BK) {
    float4 av = *reinterpret_cast<const float4*>(Ap + k0);
    float4 wv = *reinterpret_cast<const float4*>(Wp + k0);
    As[lk + 0][lm] = av.x; As[lk + 1][lm] = av.y;
    As[lk + 2][lm] = av.z; As[lk + 3][lm] = av.w;
    Ws[lk + 0][lm] = wv.x; Ws[lk + 1][lm] = wv.y;
    Ws[lk + 2][lm] = wv.z; Ws[lk + 3][lm] = wv.w;
    __syncthreads();
#pragma unroll
    for (int kk = 0; kk < BK; ++kk) {
      float4 a4 = *reinterpret_cast<const float4*>(&As[kk][ty << 2]);
      float4 w4 = *reinterpret_cast<const float4*>(&Ws[kk][tx << 2]);
      float a[4] = {a4.x, a4.y, a4.z, a4.w};
      float w[4] = {w4.x, w4.y, w4.z, w4.w};
#pragma unroll
      for (int i = 0; i < 4; ++i)
#pragma unroll
        for (int jj = 0; jj < 4; ++jj)
          acc[i][jj] = fmaf(a[i], w[jj], acc[i][jj]);
    }
    __syncthreads();
  }

  const int n0 = bn + (tx << 2);
  float b4[4];
#pragma unroll
  for (int jj = 0; jj < 4; ++jj) b4[jj] = bias[n0 + jj];
  float scale = 1.f;
  if (EPI == 1) {
    int chn = n0 / 768;
    float ls = log_s[chn];
    ls = fminf(fmaxf(ls, -10.f), 10.f);
    scale = __expf(-ls);
  }
#pragma unroll
  for (int i = 0; i < 4; ++i) {
    const int m = bm + (ty << 2) + i;
    float vals[4];
    float4 r4;
    if (EPI == 2) r4 = *reinterpret_cast<const float4*>(R + (size_t)m * N + n0);
#pragma unroll
    for (int jj = 0; jj < 4; ++jj) {
      float v = acc[i][jj];
      if (EPI == 1) v *= scale;
      v += b4[jj];
      if (EPI == 2) v += (jj == 0 ? r4.x : jj == 1 ? r4.y : jj == 2 ? r4.z : r4.w);
      if (RELU) v = fmaxf(v, 0.f);
      vals[jj] = v;
    }
    float4 o; o.x = vals[0]; o.y = vals[1]; o.z = vals[2]; o.w = vals[3];
    *reinterpret_cast<float4*>(C + (size_t)m * N + n0) = o;
  }
}

// ---------------------------------------------------------------------------
// LayerNorm over 1024 features (unchanged).
// ---------------------------------------------------------------------------
template<bool ADD>
__global__ __launch_bounds__(256) void ln_kernel(const float* __restrict__ X,
                                                 const float* __restrict__ Yad,
                                                 float* __restrict__ O)
{
  const int row = blockIdx.x, t = threadIdx.x;
  float4 v = reinterpret_cast<const float4*>(X + (size_t)row * NST)[t];
  if (ADD) {
    float4 w = reinterpret_cast<const float4*>(Yad + (size_t)row * NST)[t];
    v.x += w.x; v.y += w.y; v.z += w.z; v.w += w.w;
  }
  float s  = v.x + v.y + v.z + v.w;
  float ss = v.x * v.x + v.y * v.y + v.z * v.z + v.w * v.w;
#pragma unroll
  for (int m = 1; m < 64; m <<= 1) {
    s  += __shfl_xor(s, m, 64);
    ss += __shfl_xor(ss, m, 64);
  }
  __shared__ float ps[4], pss[4];
  const int wv = t >> 6;
  if ((t & 63) == 0) { ps[wv] = s; pss[wv] = ss; }
  __syncthreads();
  s  = ps[0] + ps[1] + ps[2] + ps[3];
  ss = pss[0] + pss[1] + pss[2] + pss[3];
  const float mean = s * (1.f / 1024.f);
  const float var  = ss * (1.f / 1024.f) - mean * mean;
  const float rstd = rsqrtf(var + 1e-5f);
  v.x = (v.x - mean) * rstd; v.y = (v.y - mean) * rstd;
  v.z = (v.z - mean) * rstd; v.w = (v.w - mean) * rstd;
  reinterpret_cast<float4*>(O + (size_t)row * NST)[t] = v;
}

// ---------------------------------------------------------------------------
// ScaleGRU scan v5 — MFMA. 1 block/channel (grid=4), 512 threads (8 waves,
// 2/SIMD). Wave w owns output-blocks nb = w*6..w*6+5 (16 gate-rows each);
// weights live as 48 named half8 B-fragments = 192 AGPR-class regs/thread
// (R1-R6 post-mortem: VALU-class live sets >96 get evicted to scratch by the
// allocator no matter what; MFMA operands go to the separately-addressed
// AGPR class, which m97/HK kernels prove allocates 192+ cleanly).
// A operand = h, uniform across all 16 A-rows (lane reads h[k] with address
// depending only on lane>>4 -> LDS broadcast): D[m][n] = hg[unit n] for every
// m,reg -> extraction reads .x from lanes 0-15. Any consistent lane->k
// permutation cancels in the K-sum since A and B use the same convention.
// Per step: 8 ds_read_b128 + 48 MFMA per wave, hg[768] via LDS, 256 gate
// threads, 2 lgkm-only barriers (vmcnt never drained).
// ---------------------------------------------------------------------------
#define SCAN_BAR() asm volatile("s_waitcnt lgkmcnt(0)\n\ts_barrier" ::: "memory")

#define DECLB(i) half8 B##i##_0, B##i##_1, B##i##_2, B##i##_3, \
                       B##i##_4, B##i##_5, B##i##_6, B##i##_7;
#define LOADB(i) \
  B##i##_0 = wp[((i)*8+0)*64]; B##i##_1 = wp[((i)*8+1)*64]; \
  B##i##_2 = wp[((i)*8+2)*64]; B##i##_3 = wp[((i)*8+3)*64]; \
  B##i##_4 = wp[((i)*8+4)*64]; B##i##_5 = wp[((i)*8+5)*64]; \
  B##i##_6 = wp[((i)*8+6)*64]; B##i##_7 = wp[((i)*8+7)*64];

// one k-chunk: load A-frag (broadcast), feed all 6 output-block chains
#define KCSTEP(kc) { \
  half8 a = hp[(kc) * 4]; \
  a0 = MFMA16(a, B0_##kc, a0); a1 = MFMA16(a, B1_##kc, a1); \
  a2 = MFMA16(a, B2_##kc, a2); a3 = MFMA16(a, B3_##kc, a3); \
  a4 = MFMA16(a, B4_##kc, a4); a5 = MFMA16(a, B5_##kc, a5); }

__global__ __attribute__((amdgpu_flat_work_group_size(512, 512)))
void scan_kernel(
    const half8* __restrict__ wB,     // layer's frag cache [4ch][384][64]
    const float* __restrict__ bn_,    // [NCH,256]
    const float* __restrict__ log_s,  // [NCH]
    const float* __restrict__ ig,     // [T, 3072]
    const float* __restrict__ h0,     // [256]
    float* __restrict__ y)            // [T, 1024]
{
  const int ch = blockIdx.x;
  const int j  = threadIdx.x;
  const int w  = j >> 6, l = j & 63;
  const float* igc = ig + ch * 768;
  float* yc        = y + ch * GHH;

  const half8* wp = wB + (size_t)ch * 24576 + (size_t)(w * 48) * 64 + l;
  DECLB(0) DECLB(1) DECLB(2) DECLB(3) DECLB(4) DECLB(5)
  LOADB(0) LOADB(1) LOADB(2) LOADB(3) LOADB(4) LOADB(5)

  __shared__ __align__(16) _Float16 hsl[GHH];  // h, f16
  __shared__ float hg[768];                    // Whh*h results

  const bool gate = (j < 256);
  float ls = log_s[ch];
  ls = fminf(fmaxf(ls, -10.f), 10.f);
  const float inv_s = __expf(-ls);
  float bnj = 0.f, h = 0.f, ir = 0.f, iz = 0.f, in_ = 0.f;
  if (gate) {
    h   = h0[j];
    bnj = bn_[ch * GHH + j];
    hsl[j] = (_Float16)h;
    ir = igc[j]; iz = igc[256 + j]; in_ = igc[512 + j];
  }
  SCAN_BAR();

  // A-frag base: lane reads h[(l>>4)*8 + e] (+ kc*32) — uniform per 16-group
  const half8* hp = reinterpret_cast<const half8*>(hsl) + (l >> 4);

  for (int t = 0; t < T_SEQ; ++t) {
    float nr = 0.f, nz = 0.f, nn = 0.f;
    if (gate && t + 1 < T_SEQ) {
      const float* p = igc + (size_t)(t + 1) * LD_IG;
      nr = p[j]; nz = p[256 + j]; nn = p[512 + j];
    }
    f32x4 a0 = {0.f, 0.f, 0.f, 0.f}, a1 = a0, a2 = a0, a3 = a0, a4 = a0, a5 = a0;
    KCSTEP(0) KCSTEP(1) KCSTEP(2) KCSTEP(3)
    KCSTEP(4) KCSTEP(5) KCSTEP(6) KCSTEP(7)
    if (l < 16) {   // D col n = lane&15; uniform-A -> any row/reg holds hg[n]
      hg[(w * 6 + 0) * 16 + l] = a0[0];
      hg[(w * 6 + 1) * 16 + l] = a1[0];
      hg[(w * 6 + 2) * 16 + l] = a2[0];
      hg[(w * 6 + 3) * 16 + l] = a3[0];
      hg[(w * 6 + 4) * 16 + l] = a4[0];
      hg[(w * 6 + 5) * 16 + l] = a5[0];
    }
    SCAN_BAR();
    if (gate) {
      const float hr = hg[j], hz = hg[256 + j], hn = hg[512 + j];
      const float rg = sigmoid_f(ir + hr);
      const float zg = sigmoid_f(iz + hz);
      const float ng = tanh_f(in_ + rg * (hn + bnj));
      const float hnew = ng + zg * (h - ng);
      h = (hnew - h) * inv_s + h;
      yc[(size_t)t * NST + j] = h;
      hsl[j] = (_Float16)h;
    }
    SCAN_BAR();
    ir = nr; iz = nz; in_ = nn;
  }
}

// ---------------------------------------------------------------------------
// Classifier second GEMM: N=10, K=1024. One block per row (unchanged).
// ---------------------------------------------------------------------------
__global__ __launch_bounds__(256) void gemv_cls(const float* __restrict__ A,
                                                const float* __restrict__ W,
                                                const float* __restrict__ b,
                                                float* __restrict__ out)
{
  const int m = blockIdx.x, t = threadIdx.x;
  float4 a = reinterpret_cast<const float4*>(A + (size_t)m * NST)[t];
  float p[10];
#pragma unroll
  for (int n = 0; n < 10; ++n) {
    float4 w = reinterpret_cast<const float4*>(W + (size_t)n * NST)[t];
    p[n] = a.x * w.x + a.y * w.y + a.z * w.z + a.w * w.w;
  }
#pragma unroll
  for (int n = 0; n < 10; ++n)
#pragma unroll
    for (int msk = 1; msk < 64; msk <<= 1) p[n] += __shfl_xor(p[n], msk, 64);
  __shared__ float red[4][10];
  const int wv = t >> 6;
  if ((t & 63) == 0) {
#pragma unroll
    for (int n = 0; n < 10; ++n) red[wv][n] = p[n];
  }
  __syncthreads();
  if (t < 10) {
    float v = red[0][t] + red[1][t] + red[2][t] + red[3][t] + b[t];
    out[(size_t)m * 10 + t] = v;
  }
}

// ---------------------------------------------------------------------------
extern "C" void kernel_launch(void* const* d_in, const int* in_sizes, int n_in,
                              void* d_out, int out_size, void* d_ws, size_t ws_size,
                              hipStream_t stream) {
  const float* inputs = (const float*)d_in[0];
  const float* h0     = (const float*)d_in[1];
  // d_in[2] = yinit_guess: unused (exact solution independent of it)
  const float* enc_w1 = (const float*)d_in[3];
  const float* enc_b1 = (const float*)d_in[4];
  const float* enc_w2 = (const float*)d_in[5];
  const float* enc_b2 = (const float*)d_in[6];
  const float* gwih   = (const float*)d_in[7];   // [3,4,768,1024]
  const float* gwhh   = (const float*)d_in[8];   // [3,4,768,256]
  const float* gb     = (const float*)d_in[9];   // [3,4,768]
  const float* gbn    = (const float*)d_in[10];  // [3,4,256]
  const float* gls    = (const float*)d_in[11];  // [3,4,1]
  const float* mw1    = (const float*)d_in[12];
  const float* mb1    = (const float*)d_in[13];
  const float* mw2    = (const float*)d_in[14];
  const float* mb2    = (const float*)d_in[15];
  const float* cw1    = (const float*)d_in[16];
  const float* cb1    = (const float*)d_in[17];
  const float* cw2    = (const float*)d_in[18];
  const float* cb2    = (const float*)d_in[19];
  float* out = (float*)d_out;

  char* ws = (char*)d_ws;
  float* bufA = (float*)ws;                          // [8192,1024] 33.5MB
  float* bufB = (float*)(ws + (size_t)33554432);     // [8192,1024] 33.5MB
  float* bufG = (float*)(ws + (size_t)67108864);     // [8192,3072] 100.7MB (ig / mlp hidden)
  half8* gw16 = (half8*)(ws + (size_t)GW_OFF);       // MFMA frag cache, 4.7MB

  const dim3 blk(256);
  const dim3 gemm_1024(8192 / 64, 1024 / 64);
  const dim3 gemm_3072(8192 / 64, 3072 / 64);

  // weight fragment cache (independent of encoder; ordered before first scan)
  prep_whh<<<dim3(1152), blk, 0, stream>>>(gwhh, gw16);

  // encoder
  gemm_f32<0, true ><<<gemm_1024, blk, 0, stream>>>(inputs, enc_w1, enc_b1, nullptr,
                                                    bufG, 8192, 1024, 128, nullptr);
  gemm_f32<0, false><<<gemm_1024, blk, 0, stream>>>(bufG, enc_w2, enc_b2, nullptr,
                                                    bufA, 8192, 1024, 1024, nullptr);
  float* x  = bufA;
  float* xb = bufB;
  for (int i = 0; i < 3; ++i) {
    ln_kernel<false><<<dim3(8192), blk, 0, stream>>>(x, nullptr, xb);
    gemm_f32<1, false><<<gemm_3072, blk, 0, stream>>>(xb, gwih + (size_t)i * 4 * 768 * 1024,
                                                      gb + (size_t)i * 3072, nullptr,
                                                      bufG, 8192, 3072, 1024,
                                                      gls + (size_t)i * 4);
    scan_kernel<<<dim3(4), dim3(512), 0, stream>>>(gw16 + (size_t)i * 98304,
                                                   gbn + (size_t)i * 1024,
                                                   gls + (size_t)i * 4,
                                                   bufG, h0, x);
    ln_kernel<true><<<dim3(8192), blk, 0, stream>>>(x, xb, x);
    gemm_f32<0, true ><<<gemm_1024, blk, 0, stream>>>(x, mw1 + (size_t)i * 1048576,
                                                      mb1 + (size_t)i * 1024, nullptr,
                                                      bufG, 8192, 1024, 1024, nullptr);
    gemm_f32<2, false><<<gemm_1024, blk, 0, stream>>>(bufG, mw2 + (size_t)i * 1048576,
                                                      mb2 + (size_t)i * 1024, x,
                                                      xb, 8192, 1024, 1024, nullptr);
    float* tmp = x; x = xb; xb = tmp;
  }
  // classifier
  gemm_f32<0, true><<<gemm_1024, blk, 0, stream>>>(x, cw1, cb1, nullptr,
                                                   bufG, 8192, 1024, 1024, nullptr);
  gemv_cls<<<dim3(8192), blk, 0, stream>>>(bufG, cw2, cb2, out);
}